// Round 2
// baseline (397.414 us; speedup 1.0000x reference)
//
#include <hip/hip_runtime.h>

#define L_ 1024
#define D_ 64
#define BH_ 64
#define NEGV (-1e15f)

typedef float f32x4 __attribute__((ext_vector_type(4)));
typedef short s16x8 __attribute__((ext_vector_type(8)));
typedef unsigned short ushort_t;

__device__ __forceinline__ unsigned short f2bf(float f) {
    unsigned int u = __builtin_bit_cast(unsigned int, f);
    u = (u + 0x7FFFu + ((u >> 16) & 1u)) >> 16;   // RNE truncate f32 -> bf16
    return (unsigned short)u;
}

__device__ __forceinline__ s16x8 load8_bf(const float* p) {
    const float4 a = *(const float4*)p;
    const float4 b = *(const float4*)(p + 4);
    s16x8 r;
    r[0] = (short)f2bf(a.x); r[1] = (short)f2bf(a.y);
    r[2] = (short)f2bf(a.z); r[3] = (short)f2bf(a.w);
    r[4] = (short)f2bf(b.x); r[5] = (short)f2bf(b.y);
    r[6] = (short)f2bf(b.z); r[7] = (short)f2bf(b.w);
    return r;
}

// V [bh][k][d] f32  ->  V^T [bh][d][k] bf16 (so PV B-frags are contiguous 16B loads)
__global__ __launch_bounds__(256)
void vt_prep(const float* __restrict__ vp, ushort_t* __restrict__ vt)
{
    const int b  = blockIdx.x;          // 256 blocks = 64 bh x 4 k-quarters
    const int bh = b >> 2;
    const int kq = (b & 3) << 8;
    const int t  = threadIdx.x;
    #pragma unroll 4
    for (int i = 0; i < 64; ++i) {
        const int widx = i * 256 + t;           // over [d=64][kk=256]
        const int d  = widx >> 8;
        const int kk = kq + (widx & 255);
        vt[(((bh << 6) + d) << 10) + kk] = f2bf(vp[(((bh << 10) + kk) << 6) + d]);
    }
}

__global__ __launch_bounds__(512, 4)
void attn_fused(const float* __restrict__ qp, const float* __restrict__ kp,
                const float* __restrict__ vp, const unsigned char* __restrict__ maskp,
                const int* __restrict__ edgep, float* __restrict__ outO,
                float* __restrict__ outA, const ushort_t* __restrict__ vtp,
                int use_vt)
{
    __shared__ __align__(16) ushort_t p_lds[32 * L_];   // 64 KB, XOR-swizzled
    __shared__ float part[16][8];
    __shared__ float gmax_s[16];
    __shared__ float gsum_s[16];

    const int tid  = threadIdx.x;
    const int lane = tid & 63;
    const int w    = tid >> 6;        // wave 0..7
    const int g    = lane >> 4;       // 0..3
    const int ln   = lane & 15;       // 0..15

    // XCD-aware swizzle: all 32 row-blocks of one bh land on one XCD (bid%8 heuristic)
    const int bid  = blockIdx.x;
    const int xcd  = bid & 7;
    const int slot = bid >> 3;                 // 0..255
    const int bh   = xcd + ((slot >> 5) << 3); // 8 bh per xcd
    const int r0   = (slot & 31) << 5;         // 32-row block

    const int c0 = w << 7;                     // this wave's 128-col slice of S

    // mask layout detection: uint8 bool bytes vs int32 (bytes 1..3 of each word all-zero)
    unsigned int det = 0;
    {
        const unsigned int* mu = (const unsigned int*)maskp;
        #pragma unroll
        for (int i = 0; i < 64; ++i) det |= mu[i];
    }
    const bool mask_i32 = ((det & 0xFFFFFF00u) == 0u);

    for (int mt = 0; mt < 2; ++mt) {
        // ---- A frags (Q rows), lane: m = ln, k = g*8 + j (+32 per kstep) ----
        const float* qbase = qp + (((bh * L_) + r0 + (mt << 4) + ln) << 6) + (g << 3);
        const s16x8 a0 = load8_bf(qbase);
        const s16x8 a1 = load8_bf(qbase + 32);

        f32x4 acc[8];
        #pragma unroll
        for (int nt = 0; nt < 8; ++nt) acc[nt] = (f32x4){0.f, 0.f, 0.f, 0.f};

        // ---- S = Q K^T over this wave's 128 cols ----
        #pragma unroll
        for (int nt = 0; nt < 8; ++nt) {
            const float* kbase = kp + (((bh * L_) + c0 + (nt << 4) + ln) << 6) + (g << 3);
            const s16x8 b0 = load8_bf(kbase);
            const s16x8 b1 = load8_bf(kbase + 32);
            acc[nt] = __builtin_amdgcn_mfma_f32_16x16x32_bf16(a0, b0, acc[nt], 0, 0, 0);
            acc[nt] = __builtin_amdgcn_mfma_f32_16x16x32_bf16(a1, b1, acc[nt], 0, 0, 0);
        }

        // ---- scale (1/8) + edge/mask -> NEG.  C layout: row=g*4+reg, col=nt*16+ln ----
        const int rl16 = g << 2;
        #pragma unroll
        for (int reg = 0; reg < 4; ++reg) {
            const int row  = r0 + (mt << 4) + rl16 + reg;
            const int* erow = edgep + ((((bh & 3) * L_) + row) << 10);
            const int mrow  = ((bh * L_) + row) << 10;
            #pragma unroll
            for (int nt = 0; nt < 8; ++nt) {
                const int col = c0 + (nt << 4) + ln;
                float val = acc[nt][reg] * 0.125f;
                int mv;
                if (mask_i32) mv = ((const int*)maskp)[mrow + col];
                else          mv = (int)maskp[mrow + col];
                if (erow[col] == 0 || mv != 0) val = NEGV;
                acc[nt][reg] = val;
            }
        }

        // ---- row max: 8 lane-local + shfl over the 16-lane group, then cross-wave LDS ----
        #pragma unroll
        for (int reg = 0; reg < 4; ++reg) {
            float m = acc[0][reg];
            #pragma unroll
            for (int nt = 1; nt < 8; ++nt) m = fmaxf(m, acc[nt][reg]);
            m = fmaxf(m, __shfl_xor(m, 1));
            m = fmaxf(m, __shfl_xor(m, 2));
            m = fmaxf(m, __shfl_xor(m, 4));
            m = fmaxf(m, __shfl_xor(m, 8));
            if (ln == 0) part[rl16 + reg][w] = m;
        }
        __syncthreads();
        if (tid < 16) {
            float m = part[tid][0];
            #pragma unroll
            for (int i = 1; i < 8; ++i) m = fmaxf(m, part[tid][i]);
            gmax_s[tid] = m;
        }
        __syncthreads();

        float gm[4], rs[4];
        #pragma unroll
        for (int reg = 0; reg < 4; ++reg) { gm[reg] = gmax_s[rl16 + reg]; rs[reg] = 0.f; }

        // ---- exp + row sum ----
        #pragma unroll
        for (int nt = 0; nt < 8; ++nt) {
            #pragma unroll
            for (int reg = 0; reg < 4; ++reg) {
                const float e = __expf(acc[nt][reg] - gm[reg]);
                acc[nt][reg] = e;
                rs[reg] += e;
            }
        }
        #pragma unroll
        for (int reg = 0; reg < 4; ++reg) {
            float s = rs[reg];
            s += __shfl_xor(s, 1);
            s += __shfl_xor(s, 2);
            s += __shfl_xor(s, 4);
            s += __shfl_xor(s, 8);
            if (ln == 0) part[rl16 + reg][w] = s;
        }
        __syncthreads();
        if (tid < 16) {
            float s = part[tid][0];
            #pragma unroll
            for (int i = 1; i < 8; ++i) s += part[tid][i];
            gsum_s[tid] = 1.0f / s;
        }
        __syncthreads();

        // ---- normalize, bf16, write P to swizzled LDS ----
        #pragma unroll
        for (int reg = 0; reg < 4; ++reg) {
            const float rinv = gsum_s[rl16 + reg];
            const int rl = (mt << 4) + rl16 + reg;            // 0..31
            const unsigned sw = (unsigned)((rl & 7) << 4);
            #pragma unroll
            for (int nt = 0; nt < 8; ++nt) {
                const int col = c0 + (nt << 4) + ln;
                const unsigned off = ((unsigned)((rl << 11) | (col << 1))) ^ sw;
                *(ushort_t*)((char*)p_lds + off) = f2bf(acc[nt][reg] * rinv);
            }
        }
    }
    __syncthreads();

    // ---- attn tile -> global f32: de-swizzle 16B bf16 chunks, widen to 2x16B f32 ----
    {
        const char* src = (const char*)p_lds;
        float* dstf = outA + (((long long)(bh * L_ + r0)) << 10);
        #pragma unroll
        for (int i = 0; i < 8; ++i) {
            const unsigned boff = (unsigned)((i * 512 + tid) << 4);
            const int rl = (int)(boff >> 11);
            const uint4 d4 = *(const uint4*)(src + (boff ^ ((rl & 7) << 4)));
            uint4 o0, o1;
            o0.x = d4.x << 16; o0.y = d4.x & 0xFFFF0000u;
            o0.z = d4.y << 16; o0.w = d4.y & 0xFFFF0000u;
            o1.x = d4.z << 16; o1.y = d4.z & 0xFFFF0000u;
            o1.z = d4.w << 16; o1.w = d4.w & 0xFFFF0000u;
            char* db = (char*)dstf + ((size_t)boff << 1);
            *(uint4*)db = o0;
            *(uint4*)(db + 16) = o1;
        }
    }

    // ---- PV: each wave computes one 16x16 O fragment over K=1024 ----
    {
        const int mt_o = w & 1;
        const int dt   = w >> 1;
        f32x4 acco = (f32x4){0.f, 0.f, 0.f, 0.f};
        const int rlA = (mt_o << 4) + ln;                 // A row (m = ln)
        const unsigned swA = (unsigned)((rlA & 7) << 4);
        const char* pl = (const char*)p_lds;
        const ushort_t* vtb = vtp + ((((bh << 6) + (dt << 4) + ln) << 10) + (g << 3));
        const float* vb0 = vp + ((bh * L_) << 6) + ((g << 3) << 6) + (dt << 4) + ln;

        for (int kt = 0; kt < 32; ++kt) {
            const unsigned offA = ((unsigned)((rlA << 11) | (kt << 6) | (g << 4))) ^ swA;
            const s16x8 a = *(const s16x8*)(pl + offA);
            s16x8 b;
            if (use_vt) {
                b = *(const s16x8*)(vtb + (kt << 5));
            } else {
                const float* vb = vb0 + (kt << 11);       // kt*32 rows * 64
                #pragma unroll
                for (int j = 0; j < 8; ++j) b[j] = (short)f2bf(vb[j << 6]);
            }
            acco = __builtin_amdgcn_mfma_f32_16x16x32_bf16(a, b, acco, 0, 0, 0);
        }

        #pragma unroll
        for (int reg = 0; reg < 4; ++reg) {
            const int row = r0 + (mt_o << 4) + (g << 2) + reg;
            outO[(((bh << 10) + row) << 6) + (dt << 4) + ln] = acco[reg];
        }
    }
}

extern "C" void kernel_launch(void* const* d_in, const int* in_sizes, int n_in,
                              void* d_out, int out_size, void* d_ws, size_t ws_size,
                              hipStream_t stream)
{
    (void)in_sizes; (void)n_in; (void)out_size;
    const float* qp = (const float*)d_in[0];
    const float* kp = (const float*)d_in[1];
    const float* vp = (const float*)d_in[2];
    const unsigned char* maskp = (const unsigned char*)d_in[3];
    const int* edgep = (const int*)d_in[4];

    float* outO = (float*)d_out;
    float* outA = outO + ((long long)BH_ * L_ * D_);   // outputs concatenated: output, attn

    ushort_t* vt = (ushort_t*)d_ws;
    const size_t vt_bytes = (size_t)BH_ * D_ * L_ * 2;
    const int use_vt = (d_ws != nullptr && ws_size >= vt_bytes) ? 1 : 0;

    if (use_vt) vt_prep<<<256, 256, 0, stream>>>(vp, vt);
    attn_fused<<<2048, 512, 0, stream>>>(qp, kp, vp, maskp, edgep, outO, outA, vt, use_vt);
}

// Round 3
// 338.360 us; speedup vs baseline: 1.1745x; 1.1745x over previous
//
#include <hip/hip_runtime.h>

#define L_ 1024
#define D_ 64
#define BH_ 64
#define NEGV (-1e15f)

typedef float f32x4 __attribute__((ext_vector_type(4)));
typedef short s16x8 __attribute__((ext_vector_type(8)));
typedef unsigned short ushort_t;

__device__ __forceinline__ unsigned short f2bf(float f) {
    unsigned int u = __builtin_bit_cast(unsigned int, f);
    u = (u + 0x7FFFu + ((u >> 16) & 1u)) >> 16;   // RNE f32 -> bf16
    return (unsigned short)u;
}

__device__ __forceinline__ s16x8 load8_bf(const float* p) {
    const float4 a = *(const float4*)p;
    const float4 b = *(const float4*)(p + 4);
    s16x8 r;
    r[0] = (short)f2bf(a.x); r[1] = (short)f2bf(a.y);
    r[2] = (short)f2bf(a.z); r[3] = (short)f2bf(a.w);
    r[4] = (short)f2bf(b.x); r[5] = (short)f2bf(b.y);
    r[6] = (short)f2bf(b.z); r[7] = (short)f2bf(b.w);
    return r;
}

// V [bh][k][d] f32 -> V^T [bh][d][k] bf16
__global__ __launch_bounds__(256)
void vt_prep(const float* __restrict__ vp, ushort_t* __restrict__ vt)
{
    const int b  = blockIdx.x;          // 256 = 64 bh x 4 k-quarters
    const int bh = b >> 2;
    const int kq = (b & 3) << 8;
    const int t  = threadIdx.x;
    #pragma unroll 4
    for (int i = 0; i < 64; ++i) {
        const int widx = i * 256 + t;   // [d=64][kk=256]
        const int d  = widx >> 8;
        const int kk = kq + (widx & 255);
        vt[(((bh << 6) + d) << 10) + kk] = f2bf(vp[(((bh << 10) + kk) << 6) + d]);
    }
}

// combined bitmask: bit=1 -> masked (edge==0 || mask!=0). [bh][row][32 words]
__global__ __launch_bounds__(256)
void bits_prep(const unsigned char* __restrict__ maskp, const int* __restrict__ edgep,
               unsigned int* __restrict__ bits)
{
    const int b    = blockIdx.x;        // 8192 = 64 bh x 128 row-octets
    const int bh   = b >> 7;
    const int row  = ((b & 127) << 3) + (threadIdx.x >> 5);
    const int word = threadIdx.x & 31;

    // mask dtype detect (uint8 bool bytes vs int32)
    unsigned int det = 0;
    const unsigned int* mu = (const unsigned int*)maskp;
    #pragma unroll
    for (int i = 0; i < 16; ++i) det |= mu[i];
    const bool mask_i32 = ((det & 0xFFFFFF00u) == 0u);

    const int col0 = word << 5;
    const int erow = (((bh & 3) << 10) + row) << 10;
    const int mrow = ((bh << 10) + row) << 10;

    unsigned int wv = 0;
    const uint4* ep = (const uint4*)(edgep + erow + col0);
    if (mask_i32) {
        const uint4* mp = (const uint4*)((const int*)maskp + mrow + col0);
        #pragma unroll
        for (int i = 0; i < 8; ++i) {
            const uint4 e = ep[i];
            const uint4 m = mp[i];
            const int j = i << 2;
            if (e.x == 0u || m.x != 0u) wv |= 1u << (j + 0);
            if (e.y == 0u || m.y != 0u) wv |= 1u << (j + 1);
            if (e.z == 0u || m.z != 0u) wv |= 1u << (j + 2);
            if (e.w == 0u || m.w != 0u) wv |= 1u << (j + 3);
        }
    } else {
        const unsigned char* mp = maskp + mrow + col0;
        const uint4 mb0 = *(const uint4*)(mp);
        const uint4 mb1 = *(const uint4*)(mp + 16);
        const unsigned int mw[8] = {mb0.x, mb0.y, mb0.z, mb0.w, mb1.x, mb1.y, mb1.z, mb1.w};
        #pragma unroll
        for (int i = 0; i < 8; ++i) {
            const uint4 e = ep[i];
            const unsigned int mm = mw[i];
            const int j = i << 2;
            if (e.x == 0u || (mm & 0x000000FFu)) wv |= 1u << (j + 0);
            if (e.y == 0u || (mm & 0x0000FF00u)) wv |= 1u << (j + 1);
            if (e.z == 0u || (mm & 0x00FF0000u)) wv |= 1u << (j + 2);
            if (e.w == 0u || (mm & 0xFF000000u)) wv |= 1u << (j + 3);
        }
    }
    bits[(((bh << 10) + row) << 5) + word] = wv;
}

template<int USE_WS>
__global__ __launch_bounds__(512, 4)
void attn_fused(const float* __restrict__ qp, const float* __restrict__ kp,
                const float* __restrict__ vp, const unsigned char* __restrict__ maskp,
                const int* __restrict__ edgep, float* __restrict__ outO,
                float* __restrict__ outA, const ushort_t* __restrict__ vtp,
                const unsigned int* __restrict__ bitsp)
{
    __shared__ __align__(16) ushort_t p_lds[16 * L_];   // 32 KB, XOR-swizzled
    __shared__ float part[16][8];
    __shared__ float gred[16];
    __shared__ float opart[4][16][17];                  // padded: conflict-free

    const int tid  = threadIdx.x;
    const int lane = tid & 63;
    const int w    = tid >> 6;        // wave 0..7
    const int g    = lane >> 4;       // 0..3
    const int ln   = lane & 15;       // 0..15

    // XCD-aware swizzle: 64 row-blocks of one bh stay on one XCD
    const int bid  = blockIdx.x;
    const int xcd  = bid & 7;
    const int slot = bid >> 3;                  // 0..511
    const int bh   = xcd + ((slot >> 6) << 3);  // 8 bh per xcd
    const int r0   = (slot & 63) << 4;          // 16-row block

    const int c0 = w << 7;                      // wave's 128-col slice

    bool mask_i32 = false;
    if (!USE_WS) {
        unsigned int det = 0;
        const unsigned int* mu = (const unsigned int*)maskp;
        #pragma unroll
        for (int i = 0; i < 64; ++i) det |= mu[i];
        mask_i32 = ((det & 0xFFFFFF00u) == 0u);
    }

    // ---- Q frags: m=ln, k=g*8+j (+32) ----
    const float* qbase = qp + (((bh * L_) + r0 + ln) << 6) + (g << 3);
    const s16x8 a0 = load8_bf(qbase);
    const s16x8 a1 = load8_bf(qbase + 32);

    f32x4 acc[8];
    #pragma unroll
    for (int nt = 0; nt < 8; ++nt) acc[nt] = (f32x4){0.f, 0.f, 0.f, 0.f};

    // ---- S = Q K^T over 128 cols ----
    #pragma unroll
    for (int nt = 0; nt < 8; ++nt) {
        const float* kbase = kp + (((bh * L_) + c0 + (nt << 4) + ln) << 6) + (g << 3);
        const s16x8 b0 = load8_bf(kbase);
        const s16x8 b1 = load8_bf(kbase + 32);
        acc[nt] = __builtin_amdgcn_mfma_f32_16x16x32_bf16(a0, b0, acc[nt], 0, 0, 0);
        acc[nt] = __builtin_amdgcn_mfma_f32_16x16x32_bf16(a1, b1, acc[nt], 0, 0, 0);
    }

    // ---- scale + mask. C layout: row=g*4+reg, col=nt*16+ln ----
    const int rl16 = g << 2;
    #pragma unroll
    for (int reg = 0; reg < 4; ++reg) {
        const int row = r0 + rl16 + reg;
        if (USE_WS) {
            // 4 words = this wave's 128-bit row slice (broadcast across lanes)
            const uint4 bw = *(const uint4*)(bitsp + (((bh << 10) + row) << 5) + (w << 2));
            const unsigned int mwv[4] = {bw.x, bw.y, bw.z, bw.w};
            #pragma unroll
            for (int nt = 0; nt < 8; ++nt) {
                const unsigned int bit = (mwv[nt >> 1] >> (((nt & 1) << 4) + ln)) & 1u;
                acc[nt][reg] = bit ? NEGV : acc[nt][reg] * 0.125f;
            }
        } else {
            const int* erow = edgep + ((((bh & 3) * L_) + row) << 10);
            const int mrow  = ((bh * L_) + row) << 10;
            #pragma unroll
            for (int nt = 0; nt < 8; ++nt) {
                const int col = c0 + (nt << 4) + ln;
                int mv;
                if (mask_i32) mv = ((const int*)maskp)[mrow + col];
                else          mv = (int)maskp[mrow + col];
                acc[nt][reg] = (erow[col] == 0 || mv != 0) ? NEGV : acc[nt][reg] * 0.125f;
            }
        }
    }

    // ---- row max ----
    #pragma unroll
    for (int reg = 0; reg < 4; ++reg) {
        float m = acc[0][reg];
        #pragma unroll
        for (int nt = 1; nt < 8; ++nt) m = fmaxf(m, acc[nt][reg]);
        m = fmaxf(m, __shfl_xor(m, 1));
        m = fmaxf(m, __shfl_xor(m, 2));
        m = fmaxf(m, __shfl_xor(m, 4));
        m = fmaxf(m, __shfl_xor(m, 8));
        if (ln == 0) part[rl16 + reg][w] = m;
    }
    __syncthreads();
    if (tid < 16) {
        float m = part[tid][0];
        #pragma unroll
        for (int i = 1; i < 8; ++i) m = fmaxf(m, part[tid][i]);
        gred[tid] = m;
    }
    __syncthreads();

    float gm[4], rs[4];
    #pragma unroll
    for (int reg = 0; reg < 4; ++reg) { gm[reg] = gred[rl16 + reg]; rs[reg] = 0.f; }

    // ---- exp + row sum ----
    #pragma unroll
    for (int nt = 0; nt < 8; ++nt) {
        #pragma unroll
        for (int reg = 0; reg < 4; ++reg) {
            const float e = __expf(acc[nt][reg] - gm[reg]);
            acc[nt][reg] = e;
            rs[reg] += e;
        }
    }
    #pragma unroll
    for (int reg = 0; reg < 4; ++reg) {
        float s = rs[reg];
        s += __shfl_xor(s, 1);
        s += __shfl_xor(s, 2);
        s += __shfl_xor(s, 4);
        s += __shfl_xor(s, 8);
        if (ln == 0) part[rl16 + reg][w] = s;
    }
    __syncthreads();
    if (tid < 16) {
        float s = part[tid][0];
        #pragma unroll
        for (int i = 1; i < 8; ++i) s += part[tid][i];
        gred[tid] = 1.0f / s;
    }
    __syncthreads();

    // ---- normalize -> bf16 -> swizzled LDS ----
    #pragma unroll
    for (int reg = 0; reg < 4; ++reg) {
        const float rinv = gred[rl16 + reg];
        const int rl = rl16 + reg;                  // 0..15
        const unsigned sw = (unsigned)((rl & 7) << 4);
        #pragma unroll
        for (int nt = 0; nt < 8; ++nt) {
            const int col = c0 + (nt << 4) + ln;
            const unsigned off = ((unsigned)((rl << 11) | (col << 1))) ^ sw;
            *(ushort_t*)((char*)p_lds + off) = f2bf(acc[nt][reg] * rinv);
        }
    }
    __syncthreads();

    // ---- attn tile -> global f32 (de-swizzle, widen, coalesced) ----
    {
        const char* src = (const char*)p_lds;
        float* dstf = outA + ((size_t)(bh * L_ + r0) << 10);
        #pragma unroll
        for (int i = 0; i < 4; ++i) {
            const unsigned boff = (unsigned)((i * 512 + tid) << 4);
            const int rl = (int)(boff >> 11);
            const uint4 d4 = *(const uint4*)(src + (boff ^ ((rl & 7) << 4)));
            uint4 o0, o1;
            o0.x = d4.x << 16; o0.y = d4.x & 0xFFFF0000u;
            o0.z = d4.y << 16; o0.w = d4.y & 0xFFFF0000u;
            o1.x = d4.z << 16; o1.y = d4.z & 0xFFFF0000u;
            o1.z = d4.w << 16; o1.w = d4.w & 0xFFFF0000u;
            char* db = (char*)dstf + ((size_t)boff << 1);
            *(uint4*)db = o0;
            *(uint4*)(db + 16) = o1;
        }
    }

    // ---- PV: wave (dt2, kh): 16x16 O fragment, K split in halves ----
    {
        const int dt2 = w & 3;       // d-tile
        const int kh  = w >> 2;      // k-half
        f32x4 acco = (f32x4){0.f, 0.f, 0.f, 0.f};
        const unsigned swA = (unsigned)((ln & 7) << 4);
        const char* pl = (const char*)p_lds;
        const ushort_t* vtb = vtp + ((((bh << 6) + (dt2 << 4) + ln) << 10) + (g << 3));
        const float* vb0 = vp + (((bh * L_) << 6) + (dt2 << 4) + ln);

        for (int kt = 0; kt < 16; ++kt) {
            const int ktg = (kh << 4) + kt;
            const unsigned offA = ((unsigned)((ln << 11) | (ktg << 6) | (g << 4))) ^ swA;
            const s16x8 a = *(const s16x8*)(pl + offA);
            s16x8 b;
            if (USE_WS) {
                b = *(const s16x8*)(vtb + (ktg << 5));
            } else {
                const float* vb = vb0 + (((ktg << 5) + (g << 3)) << 6);
                #pragma unroll
                for (int j = 0; j < 8; ++j) b[j] = (short)f2bf(vb[j << 6]);
            }
            acco = __builtin_amdgcn_mfma_f32_16x16x32_bf16(a, b, acco, 0, 0, 0);
        }

        if (kh == 1) {
            #pragma unroll
            for (int reg = 0; reg < 4; ++reg)
                opart[dt2][(g << 2) + reg][ln] = acco[reg];
        }
        __syncthreads();
        if (kh == 0) {
            #pragma unroll
            for (int reg = 0; reg < 4; ++reg) {
                const int row = r0 + (g << 2) + reg;
                outO[(((bh << 10) + row) << 6) + (dt2 << 4) + ln] =
                    acco[reg] + opart[dt2][(g << 2) + reg][ln];
            }
        }
    }
}

extern "C" void kernel_launch(void* const* d_in, const int* in_sizes, int n_in,
                              void* d_out, int out_size, void* d_ws, size_t ws_size,
                              hipStream_t stream)
{
    (void)in_sizes; (void)n_in; (void)out_size;
    const float* qp = (const float*)d_in[0];
    const float* kp = (const float*)d_in[1];
    const float* vp = (const float*)d_in[2];
    const unsigned char* maskp = (const unsigned char*)d_in[3];
    const int* edgep = (const int*)d_in[4];

    float* outO = (float*)d_out;
    float* outA = outO + ((long long)BH_ * L_ * D_);   // outputs concat: output, attn

    const size_t vt_bytes   = (size_t)BH_ * D_ * L_ * 2;          // 8 MB
    const size_t bits_bytes = (size_t)BH_ * L_ * (L_ / 8);        // 8 MB
    const int use_ws = (d_ws != nullptr && ws_size >= vt_bytes + bits_bytes) ? 1 : 0;

    ushort_t* vt = (ushort_t*)d_ws;
    unsigned int* bits = (unsigned int*)((char*)d_ws + vt_bytes);

    if (use_ws) {
        vt_prep<<<256, 256, 0, stream>>>(vp, vt);
        bits_prep<<<8192, 256, 0, stream>>>(maskp, edgep, bits);
        attn_fused<1><<<4096, 512, 0, stream>>>(qp, kp, vp, maskp, edgep, outO, outA, vt, bits);
    } else {
        attn_fused<0><<<4096, 512, 0, stream>>>(qp, kp, vp, maskp, edgep, outO, outA, vt, bits);
    }
}

// Round 4
// 333.221 us; speedup vs baseline: 1.1926x; 1.0154x over previous
//
#include <hip/hip_runtime.h>
#include <hip/hip_bf16.h>

#define L_ 1024
#define D_ 64
#define BH_ 64
#define NEGV (-1e15f)
#define QSCALE 0.18033688011112043f   // log2(e)/temperature(8): exp(S/8) == exp2(S*QSCALE)

typedef float f32x4 __attribute__((ext_vector_type(4)));
typedef short s16x8 __attribute__((ext_vector_type(8)));
typedef unsigned short ushort_t;

__device__ __forceinline__ unsigned short f2bf(float f) {
    return __builtin_bit_cast(unsigned short, __float2bfloat16(f));
}

__device__ __forceinline__ s16x8 load8_bf(const float* p) {
    const float4 a = *(const float4*)p;
    const float4 b = *(const float4*)(p + 4);
    s16x8 r;
    r[0] = (short)f2bf(a.x); r[1] = (short)f2bf(a.y);
    r[2] = (short)f2bf(a.z); r[3] = (short)f2bf(a.w);
    r[4] = (short)f2bf(b.x); r[5] = (short)f2bf(b.y);
    r[6] = (short)f2bf(b.z); r[7] = (short)f2bf(b.w);
    return r;
}

__device__ __forceinline__ s16x8 load8_bf_scale(const float* p, float c) {
    const float4 a = *(const float4*)p;
    const float4 b = *(const float4*)(p + 4);
    s16x8 r;
    r[0] = (short)f2bf(a.x * c); r[1] = (short)f2bf(a.y * c);
    r[2] = (short)f2bf(a.z * c); r[3] = (short)f2bf(a.w * c);
    r[4] = (short)f2bf(b.x * c); r[5] = (short)f2bf(b.y * c);
    r[6] = (short)f2bf(b.z * c); r[7] = (short)f2bf(b.w * c);
    return r;
}

// Fused prepass: blocks 0..8191 build the combined bitmask (bit=1 -> masked),
// blocks 8192..8447 build V^T [bh][d][k] bf16.
__global__ __launch_bounds__(256)
void prep(const float* __restrict__ vp, const unsigned char* __restrict__ maskp,
          const int* __restrict__ edgep, ushort_t* __restrict__ vt,
          unsigned int* __restrict__ bits)
{
    const int b = blockIdx.x;
    const int t = threadIdx.x;

    if (b < 8192) {
        const int bh   = b >> 7;
        const int row  = ((b & 127) << 3) + (t >> 5);
        const int word = t & 31;

        unsigned int det = 0;
        const unsigned int* mu = (const unsigned int*)maskp;
        #pragma unroll
        for (int i = 0; i < 16; ++i) det |= mu[i];
        const bool mask_i32 = ((det & 0xFFFFFF00u) == 0u);

        const int col0 = word << 5;
        const int erow = (((bh & 3) << 10) + row) << 10;
        const int mrow = ((bh << 10) + row) << 10;

        unsigned int wv = 0;
        const uint4* ep = (const uint4*)(edgep + erow + col0);
        if (mask_i32) {
            const uint4* mp = (const uint4*)((const int*)maskp + mrow + col0);
            #pragma unroll
            for (int i = 0; i < 8; ++i) {
                const uint4 e = ep[i];
                const uint4 m = mp[i];
                const int j = i << 2;
                if (e.x == 0u || m.x != 0u) wv |= 1u << (j + 0);
                if (e.y == 0u || m.y != 0u) wv |= 1u << (j + 1);
                if (e.z == 0u || m.z != 0u) wv |= 1u << (j + 2);
                if (e.w == 0u || m.w != 0u) wv |= 1u << (j + 3);
            }
        } else {
            const unsigned char* mp = maskp + mrow + col0;
            const uint4 mb0 = *(const uint4*)(mp);
            const uint4 mb1 = *(const uint4*)(mp + 16);
            const unsigned int mw[8] = {mb0.x, mb0.y, mb0.z, mb0.w, mb1.x, mb1.y, mb1.z, mb1.w};
            #pragma unroll
            for (int i = 0; i < 8; ++i) {
                const uint4 e = ep[i];
                const unsigned int mm = mw[i];
                const int j = i << 2;
                if (e.x == 0u || (mm & 0x000000FFu)) wv |= 1u << (j + 0);
                if (e.y == 0u || (mm & 0x0000FF00u)) wv |= 1u << (j + 1);
                if (e.z == 0u || (mm & 0x00FF0000u)) wv |= 1u << (j + 2);
                if (e.w == 0u || (mm & 0xFF000000u)) wv |= 1u << (j + 3);
            }
        }
        bits[(((bh << 10) + row) << 5) + word] = wv;
    } else {
        const int b2 = b - 8192;            // 0..255
        const int bh = b2 >> 2;
        const int kq = (b2 & 3) << 8;
        unsigned int* vt32 = (unsigned int*)vt;
        #pragma unroll 4
        for (int i = 0; i < 32; ++i) {
            const int p  = i * 256 + t;     // pair index over [d=64][kk2=128]
            const int d  = p >> 7;
            const int kk = kq + ((p & 127) << 1);
            const float f0 = vp[(((bh << 10) + kk) << 6) + d];
            const float f1 = vp[(((bh << 10) + kk + 1) << 6) + d];
            const unsigned int u = (unsigned int)f2bf(f0) | ((unsigned int)f2bf(f1) << 16);
            vt32[((((bh << 6) + d) << 10) + kk) >> 1] = u;
        }
    }
}

template<int USE_WS>
__global__ __launch_bounds__(512, 6)
void attn_fused(const float* __restrict__ qp, const float* __restrict__ kp,
                const float* __restrict__ vp, const unsigned char* __restrict__ maskp,
                const int* __restrict__ edgep, float* __restrict__ outO,
                float* __restrict__ outA, const ushort_t* __restrict__ vtp,
                const unsigned int* __restrict__ bitsp)
{
    __shared__ __align__(16) ushort_t p_lds[16 * L_];   // 32 KB, XOR-swizzled, UNNORMALIZED P
    __shared__ float part[16][8];
    __shared__ float gred[16];                          // 1/rowsum

    const int tid  = threadIdx.x;
    const int lane = tid & 63;
    const int w    = tid >> 6;        // wave 0..7
    const int g    = lane >> 4;       // 0..3
    const int ln   = lane & 15;       // 0..15

    // XCD-aware swizzle: 64 row-blocks of one bh stay on one XCD
    const int bid  = blockIdx.x;
    const int xcd  = bid & 7;
    const int slot = bid >> 3;                  // 0..511
    const int bh   = xcd + ((slot >> 6) << 3);  // 8 bh per xcd
    const int r0   = (slot & 63) << 4;          // 16-row block

    const int c0 = w << 7;                      // wave's 128-col slice

    bool mask_i32 = false;
    if (!USE_WS) {
        unsigned int det = 0;
        const unsigned int* mu = (const unsigned int*)maskp;
        #pragma unroll
        for (int i = 0; i < 64; ++i) det |= mu[i];
        mask_i32 = ((det & 0xFFFFFF00u) == 0u);
    }

    // ---- Q frags pre-scaled by log2(e)/8: m=ln, k=g*8+j (+32) ----
    const float* qbase = qp + (((bh * L_) + r0 + ln) << 6) + (g << 3);
    const s16x8 a0 = load8_bf_scale(qbase,      QSCALE);
    const s16x8 a1 = load8_bf_scale(qbase + 32, QSCALE);

    f32x4 acc[8];
    #pragma unroll
    for (int nt = 0; nt < 8; ++nt) acc[nt] = (f32x4){0.f, 0.f, 0.f, 0.f};

    // ---- S' = (Q*QSCALE) K^T over this wave's 128 cols ----
    #pragma unroll
    for (int nt = 0; nt < 8; ++nt) {
        const float* kbase = kp + (((bh * L_) + c0 + (nt << 4) + ln) << 6) + (g << 3);
        const s16x8 b0 = load8_bf(kbase);
        const s16x8 b1 = load8_bf(kbase + 32);
        acc[nt] = __builtin_amdgcn_mfma_f32_16x16x32_bf16(a0, b0, acc[nt], 0, 0, 0);
        acc[nt] = __builtin_amdgcn_mfma_f32_16x16x32_bf16(a1, b1, acc[nt], 0, 0, 0);
    }

    // ---- mask -> NEG (no max pass: |S'|<9 so exp2 is safe; masked -> exp2 = 0) ----
    const int rl16 = g << 2;
    #pragma unroll
    for (int reg = 0; reg < 4; ++reg) {
        const int row = r0 + rl16 + reg;
        if (USE_WS) {
            const uint4 bw = *(const uint4*)(bitsp + (((bh << 10) + row) << 5) + (w << 2));
            const unsigned int mwv[4] = {bw.x, bw.y, bw.z, bw.w};
            #pragma unroll
            for (int nt = 0; nt < 8; ++nt) {
                const unsigned int bit = (mwv[nt >> 1] >> (((nt & 1) << 4) + ln)) & 1u;
                if (bit) acc[nt][reg] = NEGV;
            }
        } else {
            const int* erow = edgep + ((((bh & 3) * L_) + row) << 10);
            const int mrow  = ((bh * L_) + row) << 10;
            #pragma unroll
            for (int nt = 0; nt < 8; ++nt) {
                const int col = c0 + (nt << 4) + ln;
                int mv;
                if (mask_i32) mv = ((const int*)maskp)[mrow + col];
                else          mv = (int)maskp[mrow + col];
                if (erow[col] == 0 || mv != 0) acc[nt][reg] = NEGV;
            }
        }
    }

    // ---- exp2 + partial row sums + unnormalized bf16 P -> swizzled LDS ----
    float rs[4] = {0.f, 0.f, 0.f, 0.f};
    #pragma unroll
    for (int reg = 0; reg < 4; ++reg) {
        const int rl = rl16 + reg;                  // 0..15
        const unsigned sw = (unsigned)((rl & 7) << 4);
        #pragma unroll
        for (int nt = 0; nt < 8; ++nt) {
            const float e = __builtin_amdgcn_exp2f(acc[nt][reg]);
            rs[reg] += e;
            const int col = c0 + (nt << 4) + ln;
            const unsigned off = ((unsigned)((rl << 11) | (col << 1))) ^ sw;
            *(ushort_t*)((char*)p_lds + off) = f2bf(e);
        }
    }
    #pragma unroll
    for (int reg = 0; reg < 4; ++reg) {
        float s = rs[reg];
        s += __shfl_xor(s, 1);
        s += __shfl_xor(s, 2);
        s += __shfl_xor(s, 4);
        s += __shfl_xor(s, 8);
        if (ln == 0) part[rl16 + reg][w] = s;
    }
    __syncthreads();                                // B1: P + partials visible
    if (tid < 16) {
        float s = part[tid][0];
        #pragma unroll
        for (int i = 1; i < 8; ++i) s += part[tid][i];
        gred[tid] = __builtin_amdgcn_rcpf(s);
    }
    __syncthreads();                                // B2: 1/sum visible

    if (w < 4) {
        // ---- PV: wave w owns d-cols [w*16, w*16+16), full K=1024; 1/sum in epilogue ----
        const int dt = w;
        f32x4 acco = (f32x4){0.f, 0.f, 0.f, 0.f};
        const unsigned swA = (unsigned)((ln & 7) << 4);
        const char* pl = (const char*)p_lds;
        const ushort_t* vtb = vtp + ((((bh << 6) + (dt << 4) + ln) << 10) + (g << 3));
        const float* vb0 = vp + (((bh * L_) << 6) + (dt << 4) + ln);

        for (int ktg = 0; ktg < 32; ++ktg) {
            const unsigned offA = ((unsigned)((ln << 11) | (ktg << 6) | (g << 4))) ^ swA;
            const s16x8 a = *(const s16x8*)(pl + offA);
            s16x8 b;
            if (USE_WS) {
                b = *(const s16x8*)(vtb + (ktg << 5));
            } else {
                const float* vb = vb0 + (((ktg << 5) + (g << 3)) << 6);
                #pragma unroll
                for (int j = 0; j < 8; ++j) b[j] = (short)f2bf(vb[j << 6]);
            }
            acco = __builtin_amdgcn_mfma_f32_16x16x32_bf16(a, b, acco, 0, 0, 0);
        }
        #pragma unroll
        for (int reg = 0; reg < 4; ++reg) {
            const int rl = (g << 2) + reg;
            outO[(((bh << 10) + r0 + rl) << 6) + (dt << 4) + ln] = acco[reg] * gred[rl];
        }
    } else {
        // ---- attn -> global f32: de-swizzle, widen, scale by 1/sum, coalesced 2x16B ----
        const int t2 = tid - 256;                   // 0..255
        const char* src = (const char*)p_lds;
        float* dstf = outA + ((size_t)(bh * L_ + r0) << 10);
        #pragma unroll
        for (int i = 0; i < 8; ++i) {
            const unsigned boff = (unsigned)((i * 256 + t2) << 4);
            const int rl = (int)(boff >> 11);
            const float rinv = gred[rl];
            const uint4 d4 = *(const uint4*)(src + (boff ^ ((rl & 7) << 4)));
            float4 f0, f1;
            f0.x = __builtin_bit_cast(float, d4.x << 16) * rinv;
            f0.y = __builtin_bit_cast(float, d4.x & 0xFFFF0000u) * rinv;
            f0.z = __builtin_bit_cast(float, d4.y << 16) * rinv;
            f0.w = __builtin_bit_cast(float, d4.y & 0xFFFF0000u) * rinv;
            f1.x = __builtin_bit_cast(float, d4.z << 16) * rinv;
            f1.y = __builtin_bit_cast(float, d4.z & 0xFFFF0000u) * rinv;
            f1.z = __builtin_bit_cast(float, d4.w << 16) * rinv;
            f1.w = __builtin_bit_cast(float, d4.w & 0xFFFF0000u) * rinv;
            char* db = (char*)dstf + ((size_t)boff << 1);
            *(float4*)db = f0;
            *(float4*)(db + 16) = f1;
        }
    }
}

extern "C" void kernel_launch(void* const* d_in, const int* in_sizes, int n_in,
                              void* d_out, int out_size, void* d_ws, size_t ws_size,
                              hipStream_t stream)
{
    (void)in_sizes; (void)n_in; (void)out_size;
    const float* qp = (const float*)d_in[0];
    const float* kp = (const float*)d_in[1];
    const float* vp = (const float*)d_in[2];
    const unsigned char* maskp = (const unsigned char*)d_in[3];
    const int* edgep = (const int*)d_in[4];

    float* outO = (float*)d_out;
    float* outA = outO + ((long long)BH_ * L_ * D_);   // outputs concat: output, attn

    const size_t vt_bytes   = (size_t)BH_ * D_ * L_ * 2;          // 8 MB
    const size_t bits_bytes = (size_t)BH_ * L_ * (L_ / 8);        // 8 MB
    const int use_ws = (d_ws != nullptr && ws_size >= vt_bytes + bits_bytes) ? 1 : 0;

    ushort_t* vt = (ushort_t*)d_ws;
    unsigned int* bits = (unsigned int*)((char*)d_ws + vt_bytes);

    if (use_ws) {
        prep<<<8448, 256, 0, stream>>>(vp, maskp, edgep, vt, bits);
        attn_fused<1><<<4096, 512, 0, stream>>>(qp, kp, vp, maskp, edgep, outO, outA, vt, bits);
    } else {
        attn_fused<0><<<4096, 512, 0, stream>>>(qp, kp, vp, maskp, edgep, outO, outA, vt, bits);
    }
}

// Round 5
// 309.324 us; speedup vs baseline: 1.2848x; 1.0773x over previous
//
#include <hip/hip_runtime.h>
#include <hip/hip_bf16.h>

#define L_ 1024
#define D_ 64
#define BH_ 64
#define NEGV (-1e15f)
#define QSCALE 0.18033688011112043f   // log2(e)/temperature(8): exp(S/8) == exp2(S*QSCALE)

typedef float f32x4 __attribute__((ext_vector_type(4)));
typedef short s16x8 __attribute__((ext_vector_type(8)));
typedef unsigned short ushort_t;

__device__ __forceinline__ unsigned short f2bf(float f) {
    return __builtin_bit_cast(unsigned short, __float2bfloat16(f));
}

__device__ __forceinline__ s16x8 load8_bf(const float* p) {
    const float4 a = *(const float4*)p;
    const float4 b = *(const float4*)(p + 4);
    s16x8 r;
    r[0] = (short)f2bf(a.x); r[1] = (short)f2bf(a.y);
    r[2] = (short)f2bf(a.z); r[3] = (short)f2bf(a.w);
    r[4] = (short)f2bf(b.x); r[5] = (short)f2bf(b.y);
    r[6] = (short)f2bf(b.z); r[7] = (short)f2bf(b.w);
    return r;
}

__device__ __forceinline__ s16x8 load8_bf_scale(const float* p, float c) {
    const float4 a = *(const float4*)p;
    const float4 b = *(const float4*)(p + 4);
    s16x8 r;
    r[0] = (short)f2bf(a.x * c); r[1] = (short)f2bf(a.y * c);
    r[2] = (short)f2bf(a.z * c); r[3] = (short)f2bf(a.w * c);
    r[4] = (short)f2bf(b.x * c); r[5] = (short)f2bf(b.y * c);
    r[6] = (short)f2bf(b.z * c); r[7] = (short)f2bf(b.w * c);
    return r;
}

// Prepass.
// blocks [0,512):    bits. edge read ONCE, applied to the 16 bh that share it.
// blocks [512,1536): V^T. L1-resident 64k x 64d tiles (16KB), coalesced 32B writes.
__global__ __launch_bounds__(256)
void prep(const float* __restrict__ vp, const unsigned char* __restrict__ maskp,
          const int* __restrict__ edgep, ushort_t* __restrict__ vt,
          unsigned int* __restrict__ bits)
{
    const int b = blockIdx.x;
    const int t = threadIdx.x;

    if (b < 512) {
        const int eb   = b >> 7;                    // edge batch 0..3
        const int row  = ((b & 127) << 3) + (t >> 5);
        const int word = t & 31;
        const int col0 = word << 5;

        // mask dtype detect (uint8 bool bytes vs int32)
        unsigned int det = 0;
        const unsigned int* mu = (const unsigned int*)maskp;
        #pragma unroll
        for (int i = 0; i < 16; ++i) det |= mu[i];
        const bool mask_i32 = ((det & 0xFFFFFF00u) == 0u);

        // edge bits once: bit j = (edge == 0)
        unsigned int ewv = 0;
        {
            const uint4* ep = (const uint4*)(edgep + (((eb << 10) + row) << 10) + col0);
            #pragma unroll
            for (int i = 0; i < 8; ++i) {
                const uint4 e = ep[i];
                const int j = i << 2;
                if (e.x == 0u) ewv |= 1u << (j + 0);
                if (e.y == 0u) ewv |= 1u << (j + 1);
                if (e.z == 0u) ewv |= 1u << (j + 2);
                if (e.w == 0u) ewv |= 1u << (j + 3);
            }
        }

        #pragma unroll 4
        for (int r = 0; r < 16; ++r) {
            const int bh = (r << 2) + eb;
            const int mrow = ((bh << 10) + row) << 10;
            unsigned int wv = ewv;
            if (mask_i32) {
                const uint4* mp = (const uint4*)((const int*)maskp + mrow + col0);
                #pragma unroll
                for (int i = 0; i < 8; ++i) {
                    const uint4 m = mp[i];
                    const int j = i << 2;
                    if (m.x != 0u) wv |= 1u << (j + 0);
                    if (m.y != 0u) wv |= 1u << (j + 1);
                    if (m.z != 0u) wv |= 1u << (j + 2);
                    if (m.w != 0u) wv |= 1u << (j + 3);
                }
            } else {
                const unsigned char* mp = maskp + mrow + col0;
                const uint4 mb0 = *(const uint4*)(mp);
                const uint4 mb1 = *(const uint4*)(mp + 16);
                const unsigned int mw[8] = {mb0.x, mb0.y, mb0.z, mb0.w,
                                            mb1.x, mb1.y, mb1.z, mb1.w};
                #pragma unroll
                for (int i = 0; i < 8; ++i) {
                    const unsigned int mm = mw[i];
                    const int j = i << 2;
                    if (mm & 0x000000FFu) wv |= 1u << (j + 0);
                    if (mm & 0x0000FF00u) wv |= 1u << (j + 1);
                    if (mm & 0x00FF0000u) wv |= 1u << (j + 2);
                    if (mm & 0xFF000000u) wv |= 1u << (j + 3);
                }
            }
            bits[(((bh << 10) + row) << 5) + word] = wv;
        }
    } else {
        // V^T: block covers V[bh][k0..k0+63][0..63] (16KB, L1-resident)
        const int idx = b - 512;                    // 0..1023
        const int bh  = idx >> 4;
        const int k0  = (idx & 15) << 6;
        const int d   = t >> 2;                     // 0..63
        const int kc  = (t & 3) << 4;               // 0,16,32,48
        const float* vsrc = vp + (((bh << 10) + k0 + kc) << 6) + d;
        unsigned int u[8];
        #pragma unroll
        for (int j = 0; j < 16; ++j) {
            const unsigned short h = f2bf(vsrc[j << 6]);
            if ((j & 1) == 0) u[j >> 1] = (unsigned int)h;
            else              u[j >> 1] |= ((unsigned int)h) << 16;
        }
        uint4* dst = (uint4*)(vt + (((bh << 6) + d) << 10) + k0 + kc);
        dst[0] = (uint4){u[0], u[1], u[2], u[3]};
        dst[1] = (uint4){u[4], u[5], u[6], u[7]};
    }
}

template<int USE_WS>
__global__ __launch_bounds__(512, 6)
void attn_fused(const float* __restrict__ qp, const float* __restrict__ kp,
                const float* __restrict__ vp, const unsigned char* __restrict__ maskp,
                const int* __restrict__ edgep, float* __restrict__ outO,
                float* __restrict__ outA, const ushort_t* __restrict__ vtp,
                const unsigned int* __restrict__ bitsp)
{
    __shared__ __align__(16) ushort_t p_lds[16 * L_];   // 32 KB, XOR-swizzled, unnormalized P
    __shared__ float part[16][8];
    __shared__ float gred[16];                          // 1/rowsum
    __shared__ float opart[4][16][17];                  // PV k-half partials (padded)

    const int tid  = threadIdx.x;
    const int lane = tid & 63;
    const int w    = tid >> 6;        // wave 0..7
    const int g    = lane >> 4;       // 0..3
    const int ln   = lane & 15;       // 0..15

    // XCD-aware swizzle: 64 row-blocks of one bh stay on one XCD
    const int bid  = blockIdx.x;
    const int xcd  = bid & 7;
    const int slot = bid >> 3;                  // 0..511
    const int bh   = xcd + ((slot >> 6) << 3);  // 8 bh per xcd
    const int r0   = (slot & 63) << 4;          // 16-row block

    const int c0 = w << 7;                      // wave's 128-col slice

    bool mask_i32 = false;
    if (!USE_WS) {
        unsigned int det = 0;
        const unsigned int* mu = (const unsigned int*)maskp;
        #pragma unroll
        for (int i = 0; i < 64; ++i) det |= mu[i];
        mask_i32 = ((det & 0xFFFFFF00u) == 0u);
    }

    // ---- Q frags pre-scaled by log2(e)/8: m=ln, k=g*8+j (+32) ----
    const float* qbase = qp + (((bh * L_) + r0 + ln) << 6) + (g << 3);
    const s16x8 a0 = load8_bf_scale(qbase,      QSCALE);
    const s16x8 a1 = load8_bf_scale(qbase + 32, QSCALE);

    f32x4 acc[8];
    #pragma unroll
    for (int nt = 0; nt < 8; ++nt) acc[nt] = (f32x4){0.f, 0.f, 0.f, 0.f};

    // ---- S' = (Q*QSCALE) K^T over this wave's 128 cols ----
    #pragma unroll
    for (int nt = 0; nt < 8; ++nt) {
        const float* kbase = kp + (((bh * L_) + c0 + (nt << 4) + ln) << 6) + (g << 3);
        const s16x8 b0 = load8_bf(kbase);
        const s16x8 b1 = load8_bf(kbase + 32);
        acc[nt] = __builtin_amdgcn_mfma_f32_16x16x32_bf16(a0, b0, acc[nt], 0, 0, 0);
        acc[nt] = __builtin_amdgcn_mfma_f32_16x16x32_bf16(a1, b1, acc[nt], 0, 0, 0);
    }

    // ---- mask -> NEG (|S'|<9 so exp2 safe; masked -> exp2 = 0) ----
    const int rl16 = g << 2;
    #pragma unroll
    for (int reg = 0; reg < 4; ++reg) {
        const int row = r0 + rl16 + reg;
        if (USE_WS) {
            const uint4 bw = *(const uint4*)(bitsp + (((bh << 10) + row) << 5) + (w << 2));
            const unsigned int mwv[4] = {bw.x, bw.y, bw.z, bw.w};
            #pragma unroll
            for (int nt = 0; nt < 8; ++nt) {
                const unsigned int bit = (mwv[nt >> 1] >> (((nt & 1) << 4) + ln)) & 1u;
                if (bit) acc[nt][reg] = NEGV;
            }
        } else {
            const int* erow = edgep + ((((bh & 3) * L_) + row) << 10);
            const int mrow  = ((bh * L_) + row) << 10;
            #pragma unroll
            for (int nt = 0; nt < 8; ++nt) {
                const int col = c0 + (nt << 4) + ln;
                int mv;
                if (mask_i32) mv = ((const int*)maskp)[mrow + col];
                else          mv = (int)maskp[mrow + col];
                if (erow[col] == 0 || mv != 0) acc[nt][reg] = NEGV;
            }
        }
    }

    // ---- exp2 + partial row sums + unnormalized bf16 P -> swizzled LDS ----
    float rs[4] = {0.f, 0.f, 0.f, 0.f};
    #pragma unroll
    for (int reg = 0; reg < 4; ++reg) {
        const int rl = rl16 + reg;
        const unsigned sw = (unsigned)((rl & 7) << 4);
        #pragma unroll
        for (int nt = 0; nt < 8; ++nt) {
            const float e = __builtin_amdgcn_exp2f(acc[nt][reg]);
            rs[reg] += e;
            const int col = c0 + (nt << 4) + ln;
            const unsigned off = ((unsigned)((rl << 11) | (col << 1))) ^ sw;
            *(ushort_t*)((char*)p_lds + off) = f2bf(e);
        }
    }
    #pragma unroll
    for (int reg = 0; reg < 4; ++reg) {
        float s = rs[reg];
        s += __shfl_xor(s, 1);
        s += __shfl_xor(s, 2);
        s += __shfl_xor(s, 4);
        s += __shfl_xor(s, 8);
        if (ln == 0) part[rl16 + reg][w] = s;
    }
    __syncthreads();                                // B1
    if (tid < 16) {
        float s = part[tid][0];
        #pragma unroll
        for (int i = 1; i < 8; ++i) s += part[tid][i];
        gred[tid] = __builtin_amdgcn_rcpf(s);
    }
    __syncthreads();                                // B2

    // ---- attn -> global f32: all 8 waves, fire-and-forget (drains under PV) ----
    {
        const char* src = (const char*)p_lds;
        float* dstf = outA + ((size_t)(bh * L_ + r0) << 10);
        #pragma unroll
        for (int i = 0; i < 4; ++i) {
            const unsigned boff = (unsigned)((i * 512 + tid) << 4);
            const int rl = (int)(boff >> 11);
            const float rinv = gred[rl];
            const uint4 d4 = *(const uint4*)(src + (boff ^ ((rl & 7) << 4)));
            float4 f0, f1;
            f0.x = __builtin_bit_cast(float, d4.x << 16) * rinv;
            f0.y = __builtin_bit_cast(float, d4.x & 0xFFFF0000u) * rinv;
            f0.z = __builtin_bit_cast(float, d4.y << 16) * rinv;
            f0.w = __builtin_bit_cast(float, d4.y & 0xFFFF0000u) * rinv;
            f1.x = __builtin_bit_cast(float, d4.z << 16) * rinv;
            f1.y = __builtin_bit_cast(float, d4.z & 0xFFFF0000u) * rinv;
            f1.z = __builtin_bit_cast(float, d4.w << 16) * rinv;
            f1.w = __builtin_bit_cast(float, d4.w & 0xFFFF0000u) * rinv;
            char* db = (char*)dstf + ((size_t)boff << 1);
            *(float4*)db = f0;
            *(float4*)(db + 16) = f1;
        }
    }

    // ---- PV: 8 waves, (dt = w&3, kh = w>>2), 16 iters, unroll-4 batched loads ----
    {
        const int dt = w & 3;
        const int kh = w >> 2;
        f32x4 acco = (f32x4){0.f, 0.f, 0.f, 0.f};
        const unsigned swA = (unsigned)((ln & 7) << 4);
        const char* pl = (const char*)p_lds;
        const ushort_t* vtb = vtp + ((((bh << 6) + (dt << 4) + ln) << 10) + (g << 3));
        const float* vb0 = vp + (((bh * L_) << 6) + (dt << 4) + ln);

        __builtin_amdgcn_s_setprio(1);
        #pragma unroll
        for (int kg = 0; kg < 4; ++kg) {
            s16x8 av[4], bv[4];
            #pragma unroll
            for (int u = 0; u < 4; ++u) {
                const int ktg = (kh << 4) + (kg << 2) + u;
                const unsigned offA = ((unsigned)((ln << 11) | (ktg << 6) | (g << 4))) ^ swA;
                av[u] = *(const s16x8*)(pl + offA);
                if (USE_WS) {
                    bv[u] = *(const s16x8*)(vtb + (ktg << 5));
                } else {
                    const float* vb = vb0 + (((ktg << 5) + (g << 3)) << 6);
                    #pragma unroll
                    for (int j = 0; j < 8; ++j) bv[u][j] = (short)f2bf(vb[j << 6]);
                }
            }
            #pragma unroll
            for (int u = 0; u < 4; ++u)
                acco = __builtin_amdgcn_mfma_f32_16x16x32_bf16(av[u], bv[u], acco, 0, 0, 0);
        }
        __builtin_amdgcn_s_setprio(0);

        if (kh == 1) {
            #pragma unroll
            for (int reg = 0; reg < 4; ++reg)
                opart[dt][rl16 + reg][ln] = acco[reg];
        }
        __syncthreads();                            // B3
        if (kh == 0) {
            #pragma unroll
            for (int reg = 0; reg < 4; ++reg) {
                const int rl = rl16 + reg;
                outO[(((bh << 10) + r0 + rl) << 6) + (dt << 4) + ln] =
                    (acco[reg] + opart[dt][rl][ln]) * gred[rl];
            }
        }
    }
}

extern "C" void kernel_launch(void* const* d_in, const int* in_sizes, int n_in,
                              void* d_out, int out_size, void* d_ws, size_t ws_size,
                              hipStream_t stream)
{
    (void)in_sizes; (void)n_in; (void)out_size;
    const float* qp = (const float*)d_in[0];
    const float* kp = (const float*)d_in[1];
    const float* vp = (const float*)d_in[2];
    const unsigned char* maskp = (const unsigned char*)d_in[3];
    const int* edgep = (const int*)d_in[4];

    float* outO = (float*)d_out;
    float* outA = outO + ((long long)BH_ * L_ * D_);   // outputs concat: output, attn

    const size_t vt_bytes   = (size_t)BH_ * D_ * L_ * 2;          // 8 MB
    const size_t bits_bytes = (size_t)BH_ * L_ * (L_ / 8);        // 8 MB
    const int use_ws = (d_ws != nullptr && ws_size >= vt_bytes + bits_bytes) ? 1 : 0;

    ushort_t* vt = (ushort_t*)d_ws;
    unsigned int* bits = (unsigned int*)((char*)d_ws + vt_bytes);

    if (use_ws) {
        prep<<<1536, 256, 0, stream>>>(vp, maskp, edgep, vt, bits);
        attn_fused<1><<<4096, 512, 0, stream>>>(qp, kp, vp, maskp, edgep, outO, outA, vt, bits);
    } else {
        attn_fused<0><<<4096, 512, 0, stream>>>(qp, kp, vp, maskp, edgep, outO, outA, vt, bits);
    }
}

// Round 6
// 246.211 us; speedup vs baseline: 1.6141x; 1.2563x over previous
//
#include <hip/hip_runtime.h>
#include <hip/hip_bf16.h>

#define L_ 1024
#define BH_ 64
#define NEGV (-1e15f)
#define QSCALE 0.18033688011112043f   // log2(e)/8: exp(S/8) == exp2(S*QSCALE)

typedef float f32x4 __attribute__((ext_vector_type(4)));
typedef short s16x8 __attribute__((ext_vector_type(8)));
typedef unsigned short ushort_t;

__device__ __forceinline__ unsigned short f2bf(float f) {
    return __builtin_bit_cast(unsigned short, __float2bfloat16(f));
}
__device__ __forceinline__ unsigned selw(uint4 v, int i) {
    switch (i) { case 0: return v.x; case 1: return v.y; case 2: return v.z; default: return v.w; }
}
__device__ __forceinline__ unsigned spread4(unsigned n) {   // bit j -> bit 4j
    return (n & 1u) | ((n & 2u) << 3) | ((n & 4u) << 6) | ((n & 8u) << 9);
}
__device__ __forceinline__ unsigned pack_bytes_nz(uint4 m) {
    unsigned u = 0;
    #pragma unroll
    for (int k = 0; k < 4; ++k) {
        const unsigned x = selw(m, k);
        u |= ((x & 0x000000FFu) ? 1u : 0u) << (k * 4 + 0);
        u |= ((x & 0x0000FF00u) ? 1u : 0u) << (k * 4 + 1);
        u |= ((x & 0x00FF0000u) ? 1u : 0u) << (k * 4 + 2);
        u |= ((x & 0xFF000000u) ? 1u : 0u) << (k * 4 + 3);
    }
    return u;
}

// 16-ballot transpose: row of 1024 i32 values -> this lane's 16-col bit word.
// TESTZERO: bit=1 if value==0 (edge); else bit=1 if value!=0 (i32 mask).
template<bool TESTZERO>
__device__ __forceinline__ unsigned row_bits_i32(uint4 e0, uint4 e1, uint4 e2, uint4 e3, int ln)
{
    #define BAL_(v) (TESTZERO ? __ballot((v) == 0u) : __ballot((v) != 0u))
    const unsigned long long b00 = BAL_(e0.x), b01 = BAL_(e0.y), b02 = BAL_(e0.z), b03 = BAL_(e0.w);
    const unsigned long long b10 = BAL_(e1.x), b11 = BAL_(e1.y), b12 = BAL_(e1.z), b13 = BAL_(e1.w);
    const unsigned long long b20 = BAL_(e2.x), b21 = BAL_(e2.y), b22 = BAL_(e2.z), b23 = BAL_(e2.w);
    const unsigned long long b30 = BAL_(e3.x), b31 = BAL_(e3.y), b32 = BAL_(e3.z), b33 = BAL_(e3.w);
    #undef BAL_
    const int q0 = ln >> 4, sh = (ln & 15) << 2;
    unsigned u = 0;
    unsigned long long bp;
    bp = q0 == 0 ? b00 : q0 == 1 ? b10 : q0 == 2 ? b20 : b30;
    u |= spread4((unsigned)((bp >> sh) & 0xF)) << 0;
    bp = q0 == 0 ? b01 : q0 == 1 ? b11 : q0 == 2 ? b21 : b31;
    u |= spread4((unsigned)((bp >> sh) & 0xF)) << 1;
    bp = q0 == 0 ? b02 : q0 == 1 ? b12 : q0 == 2 ? b22 : b32;
    u |= spread4((unsigned)((bp >> sh) & 0xF)) << 2;
    bp = q0 == 0 ? b03 : q0 == 1 ? b13 : q0 == 2 ? b23 : b33;
    u |= spread4((unsigned)((bp >> sh) & 0xF)) << 3;
    return u;
}

// prep1: edge -> combined-bit array mb, broadcast to the 16 bh sharing each edge batch.
// mb layout: [bh*1024+row][64 ushorts], word position permuted p(widx)=(widx&7)*8+(widx>>3)
// so the main kernel's wave w reads its 8 kt-words as ONE uint4 at +w*8.
__global__ __launch_bounds__(256)
void prep1(const int* __restrict__ edgep, ushort_t* __restrict__ mb)
{
    const int wv = threadIdx.x >> 6, ln = threadIdx.x & 63;
    #pragma unroll
    for (int it = 0; it < 4; ++it) {
        const int r   = (blockIdx.x << 4) + (it << 2) + wv;   // 0..4095
        const int eb  = r >> 10, row = r & 1023;
        const int rb  = ((eb << 10) + row) << 10;
        const uint4 e0 = *((const uint4*)(edgep + rb) + ln);
        const uint4 e1 = *((const uint4*)(edgep + rb + 256) + ln);
        const uint4 e2 = *((const uint4*)(edgep + rb + 512) + ln);
        const uint4 e3 = *((const uint4*)(edgep + rb + 768) + ln);
        const unsigned u = row_bits_i32<true>(e0, e1, e2, e3, ln);
        const int pp = ((ln & 7) << 3) + (ln >> 3);
        #pragma unroll
        for (int bq = 0; bq < 16; ++bq) {
            const int bh = (bq << 2) + eb;
            mb[((size_t)((bh << 10) + row) << 6) + pp] = (ushort_t)u;
        }
    }
}

// prep2: blocks [0,2048): OR mask bits into mb (coalesced).  blocks [2048,2304): V^T bf16.
__global__ __launch_bounds__(256)
void prep2(const float* __restrict__ vp, const unsigned char* __restrict__ maskp,
           ushort_t* __restrict__ mb, ushort_t* __restrict__ vt)
{
    __shared__ float tile[64][68];
    const int b = blockIdx.x;
    if (b < 2048) {
        const int wv = threadIdx.x >> 6, ln = threadIdx.x & 63;
        unsigned det = 0;
        const unsigned* mu = (const unsigned*)maskp;
        #pragma unroll
        for (int i = 0; i < 16; ++i) det |= mu[i];
        const bool mask_i32 = ((det & 0xFFFFFF00u) == 0u);
        #pragma unroll
        for (int it = 0; it < 8; ++it) {
            const int r = (b << 5) + (it << 2) + wv;          // 0..65535
            unsigned u;
            if (!mask_i32) {
                const uint4 m = *((const uint4*)(maskp + ((size_t)r << 10)) + ln);
                u = pack_bytes_nz(m);
            } else {
                const int* mp = (const int*)maskp + ((size_t)r << 10);
                const uint4 m0 = *((const uint4*)mp + ln);
                const uint4 m1 = *((const uint4*)(mp + 256) + ln);
                const uint4 m2 = *((const uint4*)(mp + 512) + ln);
                const uint4 m3 = *((const uint4*)(mp + 768) + ln);
                u = row_bits_i32<false>(m0, m1, m2, m3, ln);
            }
            const int pp = ((ln & 7) << 3) + (ln >> 3);
            mb[((size_t)r << 6) + pp] |= (ushort_t)u;
        }
    } else {
        // V [bh][k][d] f32 -> vt [bh][d][k] bf16 via LDS tile (both sides coalesced)
        const int idx = b - 2048;
        const int bh = idx >> 2, kq = (idx & 3) << 8;
        const int t = threadIdx.x;
        for (int ks = 0; ks < 4; ++ks) {
            const int k0 = kq + (ks << 6);
            {
                const int kr = t >> 2, d0 = (t & 3) << 4;
                const float* src = vp + ((size_t)(((bh << 10) + k0 + kr)) << 6) + d0;
                const float4 v0 = *(const float4*)(src);
                const float4 v1 = *(const float4*)(src + 4);
                const float4 v2 = *(const float4*)(src + 8);
                const float4 v3 = *(const float4*)(src + 12);
                *(float4*)&tile[kr][d0]      = v0;
                *(float4*)&tile[kr][d0 + 4]  = v1;
                *(float4*)&tile[kr][d0 + 8]  = v2;
                *(float4*)&tile[kr][d0 + 12] = v3;
            }
            __syncthreads();
            {
                const int d = t >> 2, kc = (t & 3) << 4;
                unsigned uu[8];
                #pragma unroll
                for (int j = 0; j < 16; ++j) {
                    const unsigned short h = f2bf(tile[kc + j][d]);
                    if (j & 1) uu[j >> 1] |= ((unsigned)h) << 16;
                    else       uu[j >> 1] = (unsigned)h;
                }
                ushort_t* dst = vt + ((size_t)((bh << 6) + d) << 10) + k0 + kc;
                *(uint4*)(dst)     = (uint4){uu[0], uu[1], uu[2], uu[3]};
                *(uint4*)(dst + 8) = (uint4){uu[4], uu[5], uu[6], uu[7]};
            }
            __syncthreads();
        }
    }
}

__device__ __forceinline__ void kwrite(ushort_t* stg, int tid, float4 r0, float4 r1, float4 r2, float4 r3)
{
    s16x8 w0, w1;
    w0[0] = (short)f2bf(r0.x); w0[1] = (short)f2bf(r0.y);
    w0[2] = (short)f2bf(r0.z); w0[3] = (short)f2bf(r0.w);
    w0[4] = (short)f2bf(r1.x); w0[5] = (short)f2bf(r1.y);
    w0[6] = (short)f2bf(r1.z); w0[7] = (short)f2bf(r1.w);
    w1[0] = (short)f2bf(r2.x); w1[1] = (short)f2bf(r2.y);
    w1[2] = (short)f2bf(r2.z); w1[3] = (short)f2bf(r2.w);
    w1[4] = (short)f2bf(r3.x); w1[5] = (short)f2bf(r3.y);
    w1[6] = (short)f2bf(r3.z); w1[7] = (short)f2bf(r3.w);
    char* base = (char*)stg + ((tid >> 2) << 7);          // row = tid/4, 128B rows
    const int sw = (tid >> 2) & 7;
    const int j0 = (tid & 3) << 1;                        // chunk pair
    *(s16x8*)(base + ((j0 ^ sw) << 4)) = w0;
    *(s16x8*)(base + (((j0 + 1) ^ sw) << 4)) = w1;
}

template<int USE_WS>
__global__ __launch_bounds__(512, 6)
void attn_main(const float* __restrict__ qp, const float* __restrict__ kp,
               const float* __restrict__ vp, const unsigned char* __restrict__ maskp,
               const int* __restrict__ edgep, float* __restrict__ outO,
               float* __restrict__ outA, const ushort_t* __restrict__ vtp,
               const ushort_t* __restrict__ mbp)
{
    __shared__ __align__(16) ushort_t p_lds[16 * 1024];   // 32 KB unnormalized P (swizzled)
    __shared__ __align__(16) ushort_t stage[8192];        // 16 KB K/V tile stage (swizzled)
    __shared__ __align__(16) ushort_t q_lds[1024];        // 2 KB Q tile (swizzled)
    __shared__ float part[16][8];
    __shared__ float gred[16];

    const int tid  = threadIdx.x;
    const int lane = tid & 63;
    const int w    = tid >> 6;
    const int g    = lane >> 4;
    const int ln   = lane & 15;

    const int bid  = blockIdx.x;
    const int xcd  = bid & 7;
    const int slot = bid >> 3;
    const int bh   = xcd + ((slot >> 6) << 3);
    const int r0   = (slot & 63) << 4;

    bool mask_i32 = false;
    if (!USE_WS) {
        unsigned det = 0;
        const unsigned* mu = (const unsigned*)maskp;
        #pragma unroll
        for (int i = 0; i < 16; ++i) det |= mu[i];
        mask_i32 = ((det & 0xFFFFFF00u) == 0u);
    }

    // ---- mask bits: 4 coalesced uint4 (rows g*4+reg, words [w][kt 0..7]) ----
    uint4 br[4];
    if (USE_WS) {
        const ushort_t* mrow = mbp + ((size_t)(((bh << 10) + r0 + (g << 2))) << 6) + (w << 3);
        br[0] = *(const uint4*)(mrow);
        br[1] = *(const uint4*)(mrow + 64);
        br[2] = *(const uint4*)(mrow + 128);
        br[3] = *(const uint4*)(mrow + 192);
    }

    // ---- issue K0 tile loads (linear, 4x float4/thread) ----
    float4 k00, k01, k02, k03;
    {
        const float4* src = (const float4*)(kp + ((size_t)(bh << 10) << 6)) + (tid << 2);
        k00 = src[0]; k01 = src[1]; k02 = src[2]; k03 = src[3];
    }
    // ---- Q tile: linear load, scale, swizzled LDS write (threads < 256) ----
    if (tid < 256) {
        const float4 qv = *((const float4*)(qp + ((size_t)((bh << 10) + r0) << 6)) + tid);
        const unsigned lo = (unsigned)f2bf(qv.x * QSCALE) | ((unsigned)f2bf(qv.y * QSCALE) << 16);
        const unsigned hi = (unsigned)f2bf(qv.z * QSCALE) | ((unsigned)f2bf(qv.w * QSCALE) << 16);
        const int qrow = tid >> 4, qch = (tid & 15) >> 1;
        char* qd = (char*)q_lds + (qrow << 7) + (((qch ^ (qrow & 7))) << 4) + ((tid & 1) << 3);
        uint2 u2; u2.x = lo; u2.y = hi;
        *(uint2*)qd = u2;
    }
    kwrite(stage, tid, k00, k01, k02, k03);
    __syncthreads();

    // ---- Q frags (ds_read_b128, swizzled) ----
    const int swp = ln & 7;
    const s16x8 a0 = *(const s16x8*)((char*)q_lds + (ln << 7) + ((g ^ swp) << 4));
    const s16x8 a1 = *(const s16x8*)((char*)q_lds + (ln << 7) + (((4 + g) ^ swp) << 4));

    float rs[4] = {0.f, 0.f, 0.f, 0.f};

    // ================= K phase: 8 tiles of 128 rows =================
    #pragma unroll
    for (int kt = 0; kt < 8; ++kt) {
        float4 nx0, nx1, nx2, nx3;
        uint4 vx0, vx1;
        if (kt < 7) {
            const float4* src = (const float4*)(kp + ((size_t)(((bh << 10) + ((kt + 1) << 7))) << 6)) + (tid << 2);
            nx0 = src[0]; nx1 = src[1]; nx2 = src[2]; nx3 = src[3];
        } else if (USE_WS) {
            const uint4* vs = (const uint4*)(vtp + ((size_t)((bh << 6) + (tid >> 3)) << 10) + ((tid & 7) << 4));
            vx0 = vs[0]; vx1 = vs[1];
        }

        const char* kb = (const char*)stage + (((w << 4) + ln) << 7);
        const s16x8 b0 = *(const s16x8*)(kb + ((g ^ swp) << 4));
        const s16x8 b1 = *(const s16x8*)(kb + (((4 + g) ^ swp) << 4));
        f32x4 acc = {0.f, 0.f, 0.f, 0.f};
        acc = __builtin_amdgcn_mfma_f32_16x16x32_bf16(a0, b0, acc, 0, 0, 0);
        acc = __builtin_amdgcn_mfma_f32_16x16x32_bf16(a1, b1, acc, 0, 0, 0);

        #pragma unroll
        for (int reg = 0; reg < 4; ++reg) {
            float sv = acc[reg];
            if (USE_WS) {
                const unsigned mw = selw(br[reg], kt >> 1);
                if ((mw >> (((kt & 1) << 4) + ln)) & 1u) sv = NEGV;
            } else {
                const int row = r0 + (g << 2) + reg;
                const int col = (kt << 7) + (w << 4) + ln;
                int mv;
                if (mask_i32) mv = ((const int*)maskp)[((size_t)((bh << 10) + row) << 10) + col];
                else          mv = (int)maskp[((size_t)((bh << 10) + row) << 10) + col];
                if (edgep[((size_t)((((bh & 3) << 10) + row)) << 10) + col] == 0 || mv != 0) sv = NEGV;
            }
            const float e = __builtin_amdgcn_exp2f(sv);
            rs[reg] += e;
            const int prow = (g << 2) + reg;
            char* pd = (char*)p_lds + (prow << 11)
                     + ((((kt << 4) + (w << 1) + (ln >> 3)) ^ (prow & 7)) << 4) + ((ln & 7) << 1);
            *(ushort_t*)pd = f2bf(e);
        }
        __syncthreads();                                   // done reading stage(kt)
        if (kt < 7) {
            kwrite(stage, tid, nx0, nx1, nx2, nx3);
        } else if (USE_WS) {
            char* bse = (char*)stage + ((tid >> 3) << 8);  // V rows 256B
            const int sw2 = (tid >> 3) & 7;
            const int ch0 = (tid & 7) << 1;
            *(uint4*)(bse + ((ch0 ^ sw2) << 4)) = vx0;
            *(uint4*)(bse + (((ch0 + 1) ^ sw2) << 4)) = vx1;
        }
        __syncthreads();                                   // stage(kt+1)/V0 visible
    }

    // ---- row sums ----
    #pragma unroll
    for (int reg = 0; reg < 4; ++reg) {
        float s = rs[reg];
        s += __shfl_xor(s, 1);
        s += __shfl_xor(s, 2);
        s += __shfl_xor(s, 4);
        s += __shfl_xor(s, 8);
        if (ln == 0) part[(g << 2) + reg][w] = s;
    }
    __syncthreads();
    if (tid < 16) {
        float s = part[tid][0];
        #pragma unroll
        for (int i = 1; i < 8; ++i) s += part[tid][i];
        gred[tid] = __builtin_amdgcn_rcpf(s);
    }
    __syncthreads();

    // ================= V phase: 8 tiles, wave (dt = w&3, kh = w>>2) =================
    const int dt = w & 3, kh = w >> 2;
    f32x4 acco = {0.f, 0.f, 0.f, 0.f};
    #pragma unroll
    for (int kt = 0; kt < 8; ++kt) {
        uint4 vx0, vx1;
        if (USE_WS && kt < 7) {
            const uint4* vs = (const uint4*)(vtp + ((size_t)((bh << 6) + (tid >> 3)) << 10)
                                             + ((kt + 1) << 7) + ((tid & 7) << 4));
            vx0 = vs[0]; vx1 = vs[1];
        }
        const char* pl = (const char*)p_lds + (ln << 11);
        const s16x8 pa0 = *(const s16x8*)(pl + ((((kt << 4) + (kh << 3) + g) ^ swp) << 4));
        const s16x8 pa1 = *(const s16x8*)(pl + ((((kt << 4) + (kh << 3) + 4 + g) ^ swp) << 4));
        s16x8 vbf0, vbf1;
        if (USE_WS) {
            const char* vb = (const char*)stage + (((dt << 4) + ln) << 8);
            vbf0 = *(const s16x8*)(vb + ((((kh << 3) + g) ^ swp) << 4));
            vbf1 = *(const s16x8*)(vb + ((((kh << 3) + 4 + g) ^ swp) << 4));
        } else {
            #pragma unroll
            for (int j = 0; j < 8; ++j) {
                const int k1 = (kt << 7) + (kh << 6) + (g << 3) + j;
                vbf0[j] = (short)f2bf(vp[((size_t)((bh << 10) + k1) << 6) + (dt << 4) + ln]);
                vbf1[j] = (short)f2bf(vp[((size_t)((bh << 10) + k1 + 32) << 6) + (dt << 4) + ln]);
            }
        }
        acco = __builtin_amdgcn_mfma_f32_16x16x32_bf16(pa0, vbf0, acco, 0, 0, 0);
        acco = __builtin_amdgcn_mfma_f32_16x16x32_bf16(pa1, vbf1, acco, 0, 0, 0);
        __syncthreads();
        if (USE_WS && kt < 7) {
            char* bse = (char*)stage + ((tid >> 3) << 8);
            const int sw2 = (tid >> 3) & 7;
            const int ch0 = (tid & 7) << 1;
            *(uint4*)(bse + ((ch0 ^ sw2) << 4)) = vx0;
            *(uint4*)(bse + (((ch0 + 1) ^ sw2) << 4)) = vx1;
        }
        __syncthreads();
    }

    // ---- kh combine (opart in freed stage) + O store ----
    float* op = (float*)stage;
    if (kh == 1) {
        #pragma unroll
        for (int reg = 0; reg < 4; ++reg)
            op[((dt << 4) + (g << 2) + reg) * 17 + ln] = acco[reg];
    }
    __syncthreads();
    if (kh == 0) {
        #pragma unroll
        for (int reg = 0; reg < 4; ++reg) {
            const int rl = (g << 2) + reg;
            const float v = (acco[reg] + op[((dt << 4) + rl) * 17 + ln]) * gred[rl];
            outO[((size_t)((bh << 10) + r0 + rl) << 6) + (dt << 4) + ln] = v;
        }
    }

    // ---- attn -> global f32 (de-swizzle, widen, scale; last so no barrier drains it) ----
    {
        const char* src = (const char*)p_lds;
        float* dstf = outA + ((size_t)((bh << 10) + r0) << 10);
        #pragma unroll
        for (int i = 0; i < 4; ++i) {
            const unsigned boff = (unsigned)((i * 512 + tid) << 4);
            const int rl = (int)(boff >> 11);
            const float rinv = gred[rl];
            const uint4 d4 = *(const uint4*)(src + (boff ^ ((rl & 7) << 4)));
            float4 f0, f1;
            f0.x = __builtin_bit_cast(float, d4.x << 16) * rinv;
            f0.y = __builtin_bit_cast(float, d4.x & 0xFFFF0000u) * rinv;
            f0.z = __builtin_bit_cast(float, d4.y << 16) * rinv;
            f0.w = __builtin_bit_cast(float, d4.y & 0xFFFF0000u) * rinv;
            f1.x = __builtin_bit_cast(float, d4.z << 16) * rinv;
            f1.y = __builtin_bit_cast(float, d4.z & 0xFFFF0000u) * rinv;
            f1.z = __builtin_bit_cast(float, d4.w << 16) * rinv;
            f1.w = __builtin_bit_cast(float, d4.w & 0xFFFF0000u) * rinv;
            char* db = (char*)dstf + ((size_t)boff << 1);
            *(float4*)db = f0;
            *(float4*)(db + 16) = f1;
        }
    }
}

extern "C" void kernel_launch(void* const* d_in, const int* in_sizes, int n_in,
                              void* d_out, int out_size, void* d_ws, size_t ws_size,
                              hipStream_t stream)
{
    (void)in_sizes; (void)n_in; (void)out_size;
    const float* qp = (const float*)d_in[0];
    const float* kp = (const float*)d_in[1];
    const float* vp = (const float*)d_in[2];
    const unsigned char* maskp = (const unsigned char*)d_in[3];
    const int* edgep = (const int*)d_in[4];

    float* outO = (float*)d_out;
    float* outA = outO + ((long long)BH_ * L_ * 64);      // outputs concat: output, attn

    const size_t vt_bytes = (size_t)BH_ * 64 * L_ * 2;    // 8 MB
    const size_t mb_bytes = (size_t)BH_ * L_ * 64 * 2;    // 8 MB
    const int use_ws = (d_ws != nullptr && ws_size >= vt_bytes + mb_bytes) ? 1 : 0;

    ushort_t* vt = (ushort_t*)d_ws;
    ushort_t* mb = (ushort_t*)((char*)d_ws + vt_bytes);

    if (use_ws) {
        prep1<<<256, 256, 0, stream>>>(edgep, mb);
        prep2<<<2304, 256, 0, stream>>>(vp, maskp, mb, vt);
        attn_main<1><<<4096, 512, 0, stream>>>(qp, kp, vp, maskp, edgep, outO, outA, vt, mb);
    } else {
        attn_main<0><<<4096, 512, 0, stream>>>(qp, kp, vp, maskp, edgep, outO, outA, vt, mb);
    }
}

// Round 7
// 239.520 us; speedup vs baseline: 1.6592x; 1.0279x over previous
//
#include <hip/hip_runtime.h>
#include <hip/hip_bf16.h>

#define L_ 1024
#define BH_ 64
#define NEGV (-1e15f)
#define QSCALE 0.18033688011112043f   // log2(e)/8: exp(S/8) == exp2(S*QSCALE)

typedef float f32x4 __attribute__((ext_vector_type(4)));
typedef short s16x8 __attribute__((ext_vector_type(8)));
typedef unsigned short ushort_t;

__device__ __forceinline__ unsigned short f2bf(float f) {
    return __builtin_bit_cast(unsigned short, __float2bfloat16(f));
}
__device__ __forceinline__ unsigned selw(uint4 v, int i) {
    switch (i) { case 0: return v.x; case 1: return v.y; case 2: return v.z; default: return v.w; }
}
__device__ __forceinline__ unsigned spread4(unsigned n) {   // bit j -> bit 4j
    return (n & 1u) | ((n & 2u) << 3) | ((n & 4u) << 6) | ((n & 8u) << 9);
}
__device__ __forceinline__ unsigned pack_bytes_nz(uint4 m) {
    unsigned u = 0;
    #pragma unroll
    for (int k = 0; k < 4; ++k) {
        const unsigned x = selw(m, k);
        u |= ((x & 0x000000FFu) ? 1u : 0u) << (k * 4 + 0);
        u |= ((x & 0x0000FF00u) ? 1u : 0u) << (k * 4 + 1);
        u |= ((x & 0x00FF0000u) ? 1u : 0u) << (k * 4 + 2);
        u |= ((x & 0xFF000000u) ? 1u : 0u) << (k * 4 + 3);
    }
    return u;
}
// async global->LDS, 16B per lane; lds base must be wave-uniform (HW adds lane*16)
__device__ __forceinline__ void gl_lds16(const void* g, void* l) {
    __builtin_amdgcn_global_load_lds(
        (const __attribute__((address_space(1))) unsigned int*)g,
        (__attribute__((address_space(3))) unsigned int*)l, 16, 0, 0);
}

// 16-ballot transpose: row of 1024 i32 -> this lane's 16-col bit word.
template<bool TESTZERO>
__device__ __forceinline__ unsigned row_bits_i32(uint4 e0, uint4 e1, uint4 e2, uint4 e3, int ln)
{
    #define BAL_(v) (TESTZERO ? __ballot((v) == 0u) : __ballot((v) != 0u))
    const unsigned long long b00 = BAL_(e0.x), b01 = BAL_(e0.y), b02 = BAL_(e0.z), b03 = BAL_(e0.w);
    const unsigned long long b10 = BAL_(e1.x), b11 = BAL_(e1.y), b12 = BAL_(e1.z), b13 = BAL_(e1.w);
    const unsigned long long b20 = BAL_(e2.x), b21 = BAL_(e2.y), b22 = BAL_(e2.z), b23 = BAL_(e2.w);
    const unsigned long long b30 = BAL_(e3.x), b31 = BAL_(e3.y), b32 = BAL_(e3.z), b33 = BAL_(e3.w);
    #undef BAL_
    const int q0 = ln >> 4, sh = (ln & 15) << 2;
    unsigned u = 0;
    unsigned long long bp;
    bp = q0 == 0 ? b00 : q0 == 1 ? b10 : q0 == 2 ? b20 : b30;
    u |= spread4((unsigned)((bp >> sh) & 0xF)) << 0;
    bp = q0 == 0 ? b01 : q0 == 1 ? b11 : q0 == 2 ? b21 : b31;
    u |= spread4((unsigned)((bp >> sh) & 0xF)) << 1;
    bp = q0 == 0 ? b02 : q0 == 1 ? b12 : q0 == 2 ? b22 : b32;
    u |= spread4((unsigned)((bp >> sh) & 0xF)) << 2;
    bp = q0 == 0 ? b03 : q0 == 1 ? b13 : q0 == 2 ? b23 : b33;
    u |= spread4((unsigned)((bp >> sh) & 0xF)) << 3;
    return u;
}

// ws layout (ushort units): K' [0,4M), V' [4M,8M), Q' [8M,12M), mb [12M,16M)
// K'/V' tile-linear: tile (bh,t) = 8192 ushorts whose linear order equals the
// desired (swizzled) LDS image, so global_load_lds can stage it verbatim.
__global__ __launch_bounds__(256)
void prep(const float* __restrict__ qp, const float* __restrict__ kp,
          const float* __restrict__ vp, const unsigned char* __restrict__ maskp,
          const int* __restrict__ edgep, ushort_t* __restrict__ ws)
{
    __shared__ float tile[128][68];
    ushort_t* Kp = ws;
    ushort_t* Vp = ws + (1u << 22);
    ushort_t* Qp = ws + (2u << 22);
    ushort_t* Mp = ws + (3u << 22);

    const int b = blockIdx.x;
    const int t = threadIdx.x;

    if (b < 1024) {
        // ---- mb: edge ballot once, OR mask bits, write final word (no RMW) ----
        const int wv = t >> 6, ln = t & 63;
        const int rid = (b << 2) + wv;          // 0..4095
        const int eb = rid >> 10, row = rid & 1023;

        unsigned det = 0;
        const unsigned* mu = (const unsigned*)maskp;
        #pragma unroll
        for (int i = 0; i < 16; ++i) det |= mu[i];
        const bool mask_i32 = ((det & 0xFFFFFF00u) == 0u);

        unsigned ewv;
        {
            const int rb = ((eb << 10) + row) << 10;
            const uint4 e0 = *((const uint4*)(edgep + rb) + ln);
            const uint4 e1 = *((const uint4*)(edgep + rb + 256) + ln);
            const uint4 e2 = *((const uint4*)(edgep + rb + 512) + ln);
            const uint4 e3 = *((const uint4*)(edgep + rb + 768) + ln);
            ewv = row_bits_i32<true>(e0, e1, e2, e3, ln);
        }
        const int pp = ((ln & 7) << 3) + (ln >> 3);
        for (int bq = 0; bq < 16; ++bq) {
            const int bh = (bq << 2) + eb;
            unsigned u = ewv;
            if (!mask_i32) {
                const uint4 m = *((const uint4*)(maskp + ((size_t)((bh << 10) + row) << 10)) + ln);
                u |= pack_bytes_nz(m);
            } else {
                const int* mp = (const int*)maskp + ((size_t)((bh << 10) + row) << 10);
                const uint4 m0 = *((const uint4*)mp + ln);
                const uint4 m1 = *((const uint4*)(mp + 256) + ln);
                const uint4 m2 = *((const uint4*)(mp + 512) + ln);
                const uint4 m3 = *((const uint4*)(mp + 768) + ln);
                u |= row_bits_i32<false>(m0, m1, m2, m3, ln);
            }
            Mp[((size_t)((bh << 10) + row) << 6) + pp] = (ushort_t)u;
        }
    } else if (b < 1536) {
        // ---- V': rows=d (256B: 16 slots), slot p holds k-chunk c = p^(d&7) ----
        const int idx = b - 1024;
        const int bh = idx >> 3, vt = idx & 7;
        const float* vsrc = vp + (((size_t)(bh << 10) + (vt << 7)) << 6);
        #pragma unroll
        for (int i = 0; i < 8; ++i) {
            const int f4 = (i << 8) + t;        // 2048 float4
            const int k = f4 >> 4, d4 = f4 & 15;
            *(float4*)&tile[k][d4 << 2] = *((const float4*)vsrc + f4);
        }
        __syncthreads();
        ushort_t* dst = Vp + ((size_t)((bh << 3) + vt) << 13);
        #pragma unroll
        for (int i = 0; i < 4; ++i) {
            const int ci = (t << 2) + i;        // 1024 chunks
            const int d = ci >> 4, p = ci & 15;
            const int c = p ^ (d & 7);
            s16x8 o;
            #pragma unroll
            for (int j = 0; j < 8; ++j) o[j] = (short)f2bf(tile[(c << 3) + j][d]);
            *(s16x8*)(dst + (ci << 3)) = o;
        }
    } else if (b < 2048) {
        // ---- K': rows=k-row (128B: 8 slots), slot s holds d-chunk c = s^(r&7) ----
        const int idx = b - 1536;
        const int bh = idx >> 3, kt = idx & 7;
        const int r = t >> 1, h = t & 1;
        const float* src = kp + (((size_t)((bh << 10) + (kt << 7) + r)) << 6) + (h << 5);
        float v[32];
        #pragma unroll
        for (int j = 0; j < 8; ++j) *(float4*)&v[j << 2] = *((const float4*)src + j);
        ushort_t* dst = Kp + ((size_t)((bh << 3) + kt) << 13) + (r << 6);
        #pragma unroll
        for (int q = 0; q < 4; ++q) {
            const int c = (h << 2) + q;
            const int s = c ^ (r & 7);
            s16x8 o;
            #pragma unroll
            for (int j = 0; j < 8; ++j) o[j] = (short)f2bf(v[(q << 3) + j]);
            *(s16x8*)(dst + (s << 3)) = o;
        }
    } else {
        // ---- Q': per (bh,rt): 64 lanes x 32B frag records, scaled by QSCALE ----
        const int bh = b - 2048;
        const int wv = t >> 6, ln = t & 63;
        for (int i = 0; i < 16; ++i) {
            const int rt = (i << 2) + wv;
            const int r = (rt << 4) + (ln & 15), gq = ln >> 4;
            const float* src = qp + (((size_t)((bh << 10) + r)) << 6) + (gq << 3);
            const float4 q0 = *(const float4*)src;
            const float4 q1 = *(const float4*)(src + 4);
            const float4 q2 = *(const float4*)(src + 32);
            const float4 q3 = *(const float4*)(src + 36);
            s16x8 a, bfr;
            a[0]=(short)f2bf(q0.x*QSCALE); a[1]=(short)f2bf(q0.y*QSCALE);
            a[2]=(short)f2bf(q0.z*QSCALE); a[3]=(short)f2bf(q0.w*QSCALE);
            a[4]=(short)f2bf(q1.x*QSCALE); a[5]=(short)f2bf(q1.y*QSCALE);
            a[6]=(short)f2bf(q1.z*QSCALE); a[7]=(short)f2bf(q1.w*QSCALE);
            bfr[0]=(short)f2bf(q2.x*QSCALE); bfr[1]=(short)f2bf(q2.y*QSCALE);
            bfr[2]=(short)f2bf(q2.z*QSCALE); bfr[3]=(short)f2bf(q2.w*QSCALE);
            bfr[4]=(short)f2bf(q3.x*QSCALE); bfr[5]=(short)f2bf(q3.y*QSCALE);
            bfr[6]=(short)f2bf(q3.z*QSCALE); bfr[7]=(short)f2bf(q3.w*QSCALE);
            ushort_t* dst = Qp + ((size_t)((bh << 6) + rt) << 10) + (ln << 4);
            *(s16x8*)(dst) = a;
            *(s16x8*)(dst + 8) = bfr;
        }
    }
}

__global__ __launch_bounds__(512, 4)
void attn_main(const ushort_t* __restrict__ ws, float* __restrict__ outO,
               float* __restrict__ outA)
{
    __shared__ __align__(16) ushort_t p_lds[16 * 1024];   // 32 KB unnormalized P
    __shared__ __align__(16) ushort_t stage[2][8192];     // 2 x 16 KB dbuf
    __shared__ float part[16][8];
    __shared__ float gred[16];

    const ushort_t* Kp = ws;
    const ushort_t* Vp = ws + (1u << 22);
    const ushort_t* Qp = ws + (2u << 22);
    const ushort_t* Mp = ws + (3u << 22);

    const int tid = threadIdx.x, lane = tid & 63, w = tid >> 6;
    const int g = lane >> 4, ln = lane & 15;
    const int bid = blockIdx.x, xcd = bid & 7, slot = bid >> 3;
    const int bh = xcd + ((slot >> 6) << 3);
    const int rt = slot & 63;
    const int r0 = rt << 4;
    const int sb = w << 1;                    // wave's 2 DMA segments (1KB each)

    // ---- prologue: Q frags, mask words, stage K tile 0 ----
    const ushort_t* qs = Qp + ((size_t)((bh << 6) + rt) << 10) + (lane << 4);
    const s16x8 a0 = *(const s16x8*)(qs);
    const s16x8 a1 = *(const s16x8*)(qs + 8);

    uint4 br[4];
    {
        const ushort_t* mrow = Mp + ((size_t)((bh << 10) + r0 + (g << 2)) << 6) + (w << 3);
        br[0] = *(const uint4*)(mrow);
        br[1] = *(const uint4*)(mrow + 64);
        br[2] = *(const uint4*)(mrow + 128);
        br[3] = *(const uint4*)(mrow + 192);
    }

    #define STAGE_(base, tt, cc)                                                   \
        gl_lds16(base + ((size_t)(bh) << 16) + ((tt) << 13) + ((sb + 0) << 9) + (lane << 3), \
                 &stage[cc][(sb + 0) << 9]);                                       \
        gl_lds16(base + ((size_t)(bh) << 16) + ((tt) << 13) + ((sb + 1) << 9) + (lane << 3), \
                 &stage[cc][(sb + 1) << 9]);

    STAGE_(Kp, 0, 0);
    __syncthreads();

    float rs[4] = {0.f, 0.f, 0.f, 0.f};

    // ================= K phase: 8 tiles, 2-phase dbuf =================
    #pragma unroll
    for (int kt = 0; kt < 8; ++kt) {
        const int cur = kt & 1, nxt = cur ^ 1;
        if (kt < 7) { STAGE_(Kp, kt + 1, nxt); }
        else        { STAGE_(Vp, 0, nxt); }    // V tile 0 overlaps reduce

        const int rw = (w << 4) + ln;
        const char* kb = (const char*)stage[cur] + (rw << 7);
        const s16x8 b0 = *(const s16x8*)(kb + (((g)     ^ (rw & 7)) << 4));
        const s16x8 b1 = *(const s16x8*)(kb + (((4 + g) ^ (rw & 7)) << 4));
        f32x4 acc = {0.f, 0.f, 0.f, 0.f};
        acc = __builtin_amdgcn_mfma_f32_16x16x32_bf16(a0, b0, acc, 0, 0, 0);
        acc = __builtin_amdgcn_mfma_f32_16x16x32_bf16(a1, b1, acc, 0, 0, 0);

        #pragma unroll
        for (int reg = 0; reg < 4; ++reg) {
            float sv = acc[reg];
            const unsigned mw = selw(br[reg], kt >> 1);
            if ((mw >> (((kt & 1) << 4) + ln)) & 1u) sv = NEGV;
            const float e = __builtin_amdgcn_exp2f(sv);
            rs[reg] += e;
            const int prow = (g << 2) + reg;
            char* pd = (char*)p_lds + (prow << 11)
                     + ((((kt << 4) + (w << 1) + (ln >> 3)) ^ (prow & 7)) << 4)
                     + ((ln & 7) << 1);
            *(ushort_t*)pd = f2bf(e);
        }
        __syncthreads();
    }

    // ---- row sums -> gred ----
    #pragma unroll
    for (int reg = 0; reg < 4; ++reg) {
        float s = rs[reg];
        s += __shfl_xor(s, 1);
        s += __shfl_xor(s, 2);
        s += __shfl_xor(s, 4);
        s += __shfl_xor(s, 8);
        if (ln == 0) part[(g << 2) + reg][w] = s;
    }
    __syncthreads();
    if (tid < 16) {
        float s = part[tid][0];
        #pragma unroll
        for (int i = 1; i < 8; ++i) s += part[tid][i];
        gred[tid] = __builtin_amdgcn_rcpf(s);
    }
    __syncthreads();

    // ================= V phase: 8 tiles, 2-phase dbuf =================
    const int dt = w & 3, kh = w >> 2;
    f32x4 acco = {0.f, 0.f, 0.f, 0.f};
    #pragma unroll
    for (int ut = 0; ut < 8; ++ut) {
        const int cur = ut & 1, nxt = cur ^ 1;
        if (ut < 7) { STAGE_(Vp, ut + 1, nxt); }

        const char* pl = (const char*)p_lds + (ln << 11);
        const s16x8 pa0 = *(const s16x8*)(pl + ((((ut << 4) + (kh << 3) + g)     ^ (ln & 7)) << 4));
        const s16x8 pa1 = *(const s16x8*)(pl + ((((ut << 4) + (kh << 3) + 4 + g) ^ (ln & 7)) << 4));
        const char* vb = (const char*)stage[cur] + (((dt << 4) + ln) << 8);
        const s16x8 vb0 = *(const s16x8*)(vb + ((((kh << 3) + g)     ^ (ln & 7)) << 4));
        const s16x8 vb1 = *(const s16x8*)(vb + ((((kh << 3) + 4 + g) ^ (ln & 7)) << 4));
        acco = __builtin_amdgcn_mfma_f32_16x16x32_bf16(pa0, vb0, acco, 0, 0, 0);
        acco = __builtin_amdgcn_mfma_f32_16x16x32_bf16(pa1, vb1, acco, 0, 0, 0);
        __syncthreads();
    }
    #undef STAGE_

    // ---- kh combine (opart overlays stage[0]) + O store ----
    float* op = (float*)&stage[0][0];
    if (kh == 1) {
        #pragma unroll
        for (int reg = 0; reg < 4; ++reg)
            op[((dt << 4) + (g << 2) + reg) * 17 + ln] = acco[reg];
    }
    __syncthreads();
    if (kh == 0) {
        #pragma unroll
        for (int reg = 0; reg < 4; ++reg) {
            const int rl = (g << 2) + reg;
            outO[((size_t)((bh << 10) + r0 + rl) << 6) + (dt << 4) + ln] =
                (acco[reg] + op[((dt << 4) + rl) * 17 + ln]) * gred[rl];
        }
    }

    // ---- attn -> global f32 (de-swizzle, widen, scale) ----
    {
        const char* src = (const char*)p_lds;
        float* dstf = outA + ((size_t)((bh << 10) + r0) << 10);
        #pragma unroll
        for (int i = 0; i < 4; ++i) {
            const unsigned boff = (unsigned)((i * 512 + tid) << 4);
            const int rl = (int)(boff >> 11);
            const float rinv = gred[rl];
            const uint4 d4 = *(const uint4*)(src + (boff ^ ((rl & 7) << 4)));
            float4 f0, f1;
            f0.x = __builtin_bit_cast(float, d4.x << 16) * rinv;
            f0.y = __builtin_bit_cast(float, d4.x & 0xFFFF0000u) * rinv;
            f0.z = __builtin_bit_cast(float, d4.y << 16) * rinv;
            f0.w = __builtin_bit_cast(float, d4.y & 0xFFFF0000u) * rinv;
            f1.x = __builtin_bit_cast(float, d4.z << 16) * rinv;
            f1.y = __builtin_bit_cast(float, d4.z & 0xFFFF0000u) * rinv;
            f1.z = __builtin_bit_cast(float, d4.w << 16) * rinv;
            f1.w = __builtin_bit_cast(float, d4.w & 0xFFFF0000u) * rinv;
            char* db = (char*)dstf + ((size_t)boff << 1);
            *(float4*)db = f0;
            *(float4*)(db + 16) = f1;
        }
    }
}

// -------- fallback (no workspace): direct-load version, correctness-only --------
__global__ __launch_bounds__(512)
void attn_fb(const float* __restrict__ qp, const float* __restrict__ kp,
             const float* __restrict__ vp, const unsigned char* __restrict__ maskp,
             const int* __restrict__ edgep, float* __restrict__ outO,
             float* __restrict__ outA)
{
    __shared__ __align__(16) ushort_t p_lds[16 * 1024];
    __shared__ float part[16][8];
    __shared__ float gred[16];
    __shared__ float opart[4][16][17];

    const int tid = threadIdx.x, lane = tid & 63, w = tid >> 6;
    const int g = lane >> 4, ln = lane & 15;
    const int bid = blockIdx.x, xcd = bid & 7, slot = bid >> 3;
    const int bh = xcd + ((slot >> 6) << 3);
    const int r0 = (slot & 63) << 4;
    const int c0 = w << 7;

    unsigned det = 0;
    const unsigned* mu = (const unsigned*)maskp;
    #pragma unroll
    for (int i = 0; i < 16; ++i) det |= mu[i];
    const bool mask_i32 = ((det & 0xFFFFFF00u) == 0u);

    const float* qb = qp + (((size_t)((bh << 10) + r0 + ln)) << 6) + (g << 3);
    s16x8 a0, a1;
    #pragma unroll
    for (int j = 0; j < 8; ++j) {
        a0[j] = (short)f2bf(qb[j] * QSCALE);
        a1[j] = (short)f2bf(qb[j + 32] * QSCALE);
    }

    f32x4 acc[8];
    #pragma unroll
    for (int nt = 0; nt < 8; ++nt) acc[nt] = (f32x4){0.f, 0.f, 0.f, 0.f};
    #pragma unroll
    for (int nt = 0; nt < 8; ++nt) {
        const float* kb = kp + (((size_t)((bh << 10) + c0 + (nt << 4) + ln)) << 6) + (g << 3);
        s16x8 b0, b1;
        #pragma unroll
        for (int j = 0; j < 8; ++j) {
            b0[j] = (short)f2bf(kb[j]);
            b1[j] = (short)f2bf(kb[j + 32]);
        }
        acc[nt] = __builtin_amdgcn_mfma_f32_16x16x32_bf16(a0, b0, acc[nt], 0, 0, 0);
        acc[nt] = __builtin_amdgcn_mfma_f32_16x16x32_bf16(a1, b1, acc[nt], 0, 0, 0);
    }

    float rs[4] = {0.f, 0.f, 0.f, 0.f};
    #pragma unroll
    for (int reg = 0; reg < 4; ++reg) {
        const int row = r0 + (g << 2) + reg;
        #pragma unroll
        for (int nt = 0; nt < 8; ++nt) {
            const int col = c0 + (nt << 4) + ln;
            float sv = acc[nt][reg];
            int mv;
            if (mask_i32) mv = ((const int*)maskp)[((size_t)((bh << 10) + row) << 10) + col];
            else          mv = (int)maskp[((size_t)((bh << 10) + row) << 10) + col];
            if (edgep[((size_t)((((bh & 3) << 10) + row)) << 10) + col] == 0 || mv != 0) sv = NEGV;
            const float e = __builtin_amdgcn_exp2f(sv);
            rs[reg] += e;
            const int rl = (g << 2) + reg;
            const unsigned off = ((unsigned)((rl << 11) | (col << 1))) ^ ((rl & 7) << 4);
            *(ushort_t*)((char*)p_lds + off) = f2bf(e);
        }
    }
    #pragma unroll
    for (int reg = 0; reg < 4; ++reg) {
        float s = rs[reg];
        s += __shfl_xor(s, 1);
        s += __shfl_xor(s, 2);
        s += __shfl_xor(s, 4);
        s += __shfl_xor(s, 8);
        if (ln == 0) part[(g << 2) + reg][w] = s;
    }
    __syncthreads();
    if (tid < 16) {
        float s = part[tid][0];
        #pragma unroll
        for (int i = 1; i < 8; ++i) s += part[tid][i];
        gred[tid] = __builtin_amdgcn_rcpf(s);
    }
    __syncthreads();

    const int dt = w & 3, kh = w >> 2;
    f32x4 acco = {0.f, 0.f, 0.f, 0.f};
    for (int kt = 0; kt < 16; ++kt) {
        const int ktg = (kh << 4) + kt;
        const unsigned offA = ((unsigned)((ln << 11) | (ktg << 6) | (g << 4))) ^ ((ln & 7) << 4);
        const s16x8 pa = *(const s16x8*)((const char*)p_lds + offA);
        s16x8 vb;
        #pragma unroll
        for (int j = 0; j < 8; ++j)
            vb[j] = (short)f2bf(vp[((size_t)((bh << 10) + (ktg << 5) + (g << 3) + j) << 6) + (dt << 4) + ln]);
        acco = __builtin_amdgcn_mfma_f32_16x16x32_bf16(pa, vb, acco, 0, 0, 0);
    }
    if (kh == 1) {
        #pragma unroll
        for (int reg = 0; reg < 4; ++reg)
            opart[dt][(g << 2) + reg][ln] = acco[reg];
    }
    __syncthreads();
    if (kh == 0) {
        #pragma unroll
        for (int reg = 0; reg < 4; ++reg) {
            const int rl = (g << 2) + reg;
            outO[((size_t)((bh << 10) + r0 + rl) << 6) + (dt << 4) + ln] =
                (acco[reg] + opart[dt][rl][ln]) * gred[rl];
        }
    }
    {
        const char* src = (const char*)p_lds;
        float* dstf = outA + ((size_t)((bh << 10) + r0) << 10);
        #pragma unroll
        for (int i = 0; i < 4; ++i) {
            const unsigned boff = (unsigned)((i * 512 + tid) << 4);
            const int rl = (int)(boff >> 11);
            const float rinv = gred[rl];
            const uint4 d4 = *(const uint4*)(src + (boff ^ ((rl & 7) << 4)));
            float4 f0, f1;
            f0.x = __builtin_bit_cast(float, d4.x << 16) * rinv;
            f0.y = __builtin_bit_cast(float, d4.x & 0xFFFF0000u) * rinv;
            f0.z = __builtin_bit_cast(float, d4.y << 16) * rinv;
            f0.w = __builtin_bit_cast(float, d4.y & 0xFFFF0000u) * rinv;
            f1.x = __builtin_bit_cast(float, d4.z << 16) * rinv;
            f1.y = __builtin_bit_cast(float, d4.z & 0xFFFF0000u) * rinv;
            f1.z = __builtin_bit_cast(float, d4.w << 16) * rinv;
            f1.w = __builtin_bit_cast(float, d4.w & 0xFFFF0000u) * rinv;
            char* db = (char*)dstf + ((size_t)boff << 1);
            *(float4*)db = f0;
            *(float4*)(db + 16) = f1;
        }
    }
}

extern "C" void kernel_launch(void* const* d_in, const int* in_sizes, int n_in,
                              void* d_out, int out_size, void* d_ws, size_t ws_size,
                              hipStream_t stream)
{
    (void)in_sizes; (void)n_in; (void)out_size;
    const float* qp = (const float*)d_in[0];
    const float* kp = (const float*)d_in[1];
    const float* vp = (const float*)d_in[2];
    const unsigned char* maskp = (const unsigned char*)d_in[3];
    const int* edgep = (const int*)d_in[4];

    float* outO = (float*)d_out;
    float* outA = outO + ((long long)BH_ * L_ * 64);       // outputs concat: output, attn

    const size_t need = (size_t)32 * 1024 * 1024;          // K'+V'+Q'+mb
    if (d_ws != nullptr && ws_size >= need) {
        ushort_t* ws = (ushort_t*)d_ws;
        prep<<<2112, 256, 0, stream>>>(qp, kp, vp, maskp, edgep, ws);
        attn_main<<<4096, 512, 0, stream>>>(ws, outO, outA);
    } else {
        attn_fb<<<4096, 512, 0, stream>>>(qp, kp, vp, maskp, edgep, outO, outA);
    }
}